// Round 2
// baseline (702.087 us; speedup 1.0000x reference)
//
#include <hip/hip_runtime.h>
#include <math.h>

#define Hh 8
#define DKc 128
#define DVc 256
#define CHUNKc 64
#define GLNf 16.0f
#define EPSf 1e-5f

#define Bb 4
#define Tt 2048
#define Dd 2048
#define KDIM 1024
#define VDIM 2048
#define Mrows 8192
#define NCHUNK 32

typedef short bf16x8 __attribute__((ext_vector_type(8)));
typedef float f32x4 __attribute__((ext_vector_type(4)));

__device__ inline ushort f2bf(float f) {
  unsigned u = __float_as_uint(f);
  unsigned r = (u + 0x7fffu + ((u >> 16) & 1u)) >> 16;
  return (ushort)r;
}
__device__ inline float bf2f(ushort u) {
  return __uint_as_float(((unsigned)u) << 16);
}

// ---------------- RMSNorm + bf16 cast: one block per row ----------------
__global__ __launch_bounds__(256) void rmsnorm_kernel(const float* __restrict__ seg,
                                                      const float* __restrict__ norm_w,
                                                      ushort* __restrict__ xb) {
  int row = blockIdx.x;
  int t = threadIdx.x;
  const float4* p = (const float4*)(seg + (size_t)row * Dd);
  float4 a = p[t];
  float4 b = p[t + 256];
  float ss = a.x * a.x + a.y * a.y + a.z * a.z + a.w * a.w +
             b.x * b.x + b.y * b.y + b.z * b.z + b.w * b.w;
#pragma unroll
  for (int off = 32; off > 0; off >>= 1) ss += __shfl_down(ss, off);
  __shared__ float red[4];
  if ((t & 63) == 0) red[t >> 6] = ss;
  __syncthreads();
  float tot = red[0] + red[1] + red[2] + red[3];
  float scale = rsqrtf(tot * (1.0f / (float)Dd) + EPSf);
  const float4* w4 = (const float4*)norm_w;
  float4 wa = w4[t], wb = w4[t + 256];
  ushort4 oa, ob;
  oa.x = f2bf(a.x * scale * wa.x);
  oa.y = f2bf(a.y * scale * wa.y);
  oa.z = f2bf(a.z * scale * wa.z);
  oa.w = f2bf(a.w * scale * wa.w);
  ob.x = f2bf(b.x * scale * wb.x);
  ob.y = f2bf(b.y * scale * wb.y);
  ob.z = f2bf(b.z * scale * wb.z);
  ob.w = f2bf(b.w * scale * wb.w);
  ushort4* o4 = (ushort4*)(xb + (size_t)row * Dd);
  o4[t] = oa;
  o4[t + 256] = ob;
}

// ------------- transpose fp32 [K][N] -> bf16 [NP][K], zero-pad rows >= N -------------
__global__ __launch_bounds__(256) void transpose_cast_kernel(const float* __restrict__ in,
                                                             ushort* __restrict__ out,
                                                             int N, int NP) {
  const int K = 2048;
  __shared__ float tile[32][33];
  int k0 = blockIdx.x * 32;
  int n0 = blockIdx.y * 32;
  int tx = threadIdx.x & 31;
  int ty = threadIdx.x >> 5;  // 0..7
#pragma unroll
  for (int i = 0; i < 32; i += 8) {
    int k = k0 + ty + i;
    int n = n0 + tx;
    float v = (n < N) ? in[(size_t)k * N + n] : 0.0f;
    tile[ty + i][tx] = v;
  }
  __syncthreads();
#pragma unroll
  for (int i = 0; i < 32; i += 8) {
    int n = n0 + ty + i;
    int k = k0 + tx;
    out[(size_t)n * K + k] = f2bf(tile[tx][ty + i]);
  }
}

// ------------- bf16 MFMA GEMM: C[M][N] = A[M][K] * Bt[N][K]^T  (m97-style) -------------
// BF16OUT: store C as bf16 (ushort) instead of fp32.
template <bool BF16OUT>
__global__ __launch_bounds__(256) void gemm_kernel(const ushort* __restrict__ A,
                                                   const ushort* __restrict__ Bt,
                                                   void* __restrict__ Cv,
                                                   int N, int K) {
  __shared__ __align__(16) ushort As[128 * 32];
  __shared__ __align__(16) ushort Bs[128 * 32];
  int bm = blockIdx.x, bn = blockIdx.y;
  int wave = threadIdx.x >> 6;
  int lane = threadIdx.x & 63;
  int wm = wave >> 1, wn = wave & 1;
  int lrow = lane & 15;
  int quad = lane >> 4;
  int rowInChunk = lane >> 2;      // 0..15
  int kElem = (lane & 3) * 8;      // 0,8,16,24

  f32x4 acc[4][4] = {};
  const size_t Kz = (size_t)K;

  for (int kk = 0; kk < K; kk += 32) {
#pragma unroll
    for (int r = 0; r < 2; ++r) {
      int chunk = wave * 2 + r;  // 0..7
      int arow = chunk * 16 + rowInChunk;
      const ushort* ga = A + ((size_t)(bm * 128 + arow)) * Kz + kk + kElem;
      const ushort* gb = Bt + ((size_t)(bn * 128 + arow)) * Kz + kk + kElem;
      __builtin_amdgcn_global_load_lds((__attribute__((address_space(1))) void*)ga,
                                       (__attribute__((address_space(3))) void*)(As + chunk * 512),
                                       16, 0, 0);
      __builtin_amdgcn_global_load_lds((__attribute__((address_space(1))) void*)gb,
                                       (__attribute__((address_space(3))) void*)(Bs + chunk * 512),
                                       16, 0, 0);
    }
    __syncthreads();
    bf16x8 af[4], bfr[4];
#pragma unroll
    for (int i = 0; i < 4; ++i) {
      int r = wm * 64 + i * 16 + lrow;
      af[i] = *(const bf16x8*)(As + r * 32 + quad * 8);
    }
#pragma unroll
    for (int j = 0; j < 4; ++j) {
      int r = wn * 64 + j * 16 + lrow;
      bfr[j] = *(const bf16x8*)(Bs + r * 32 + quad * 8);
    }
#pragma unroll
    for (int i = 0; i < 4; ++i)
#pragma unroll
      for (int j = 0; j < 4; ++j)
        acc[i][j] = __builtin_amdgcn_mfma_f32_16x16x32_bf16(af[i], bfr[j], acc[i][j], 0, 0, 0);
    __syncthreads();
  }

#pragma unroll
  for (int i = 0; i < 4; ++i) {
    int rbase = bm * 128 + wm * 64 + i * 16 + quad * 4;
#pragma unroll
    for (int j = 0; j < 4; ++j) {
      int col = bn * 128 + wn * 64 + j * 16 + lrow;
#pragma unroll
      for (int rg = 0; rg < 4; ++rg) {
        if (BF16OUT)
          ((ushort*)Cv)[(size_t)(rbase + rg) * N + col] = f2bf(acc[i][j][rg]);
        else
          ((float*)Cv)[(size_t)(rbase + rg) * N + col] = acc[i][j][rg];
      }
    }
  }
}

// ------------- gate: gk = log_sigmoid(g1 @ Wg2 + bg2) / GLN -------------
__global__ __launch_bounds__(256) void gate_kernel(const float* __restrict__ g1,
                                                   const float* __restrict__ Wg2,
                                                   const float* __restrict__ bg2,
                                                   float* __restrict__ gk) {
  int idx = blockIdx.x * 256 + threadIdx.x;
  int row = idx >> 10;
  int kd = idx & 1023;
  const float* g1r = g1 + (size_t)row * 128;
  float g = bg2[kd];
#pragma unroll
  for (int r = 0; r < 16; ++r) g = fmaf(g1r[r], Wg2[r * 1024 + kd], g);
  float ls;
  if (g >= 0.f)
    ls = -log1pf(expf(-g));
  else
    ls = g - log1pf(expf(g));
  gk[idx] = ls * (1.0f / GLNf);
}

// ------------- chunked gated scan: S = S*decay + (k*decay_k)^T @ v -------------
__global__ __launch_bounds__(256) void scan_kernel(const ushort* __restrict__ kbuf,  // [8192][1024] bf16
                                                   const ushort* __restrict__ vbuf,  // [8192][2048] bf16
                                                   const float* __restrict__ gkbuf,  // [8192][1024] f32
                                                   const float* __restrict__ S0,     // [4][8][128][256]
                                                   float* __restrict__ out) {
  __shared__ __align__(16) float ldsg[CHUNKc * DKc];  // 32 KB
  __shared__ __align__(16) float ldsv[CHUNKc * 64];   // 16 KB
  __shared__ float cdec[DKc];
  __shared__ float blast[DKc];
  int vt = blockIdx.x;  // 0..3
  int bh = blockIdx.y;  // 0..31
  int b = bh >> 3, h = bh & 7;
  int t = threadIdx.x;
  int k0 = (t & 31) * 4;
  int v0 = (t >> 5) * 8;

  float S[4][8];
  size_t sbase = (size_t)bh * DKc * DVc + (size_t)vt * 64;
#pragma unroll
  for (int i = 0; i < 4; ++i)
#pragma unroll
    for (int j = 0; j < 8; ++j)
      S[i][j] = S0[sbase + (size_t)(k0 + i) * DVc + v0 + j];

  for (int n = 0; n < NCHUNK; ++n) {
    size_t trow = (size_t)b * Tt + (size_t)n * CHUNKc;
    __syncthreads();  // protect LDS from previous iteration's readers
#pragma unroll 4
    for (int i = 0; i < 32; ++i) {
      int flat = i * 256 + t;
      int c = flat >> 7, kd = flat & 127;
      ldsg[flat] = gkbuf[(trow + c) * KDIM + h * DKc + kd];
    }
#pragma unroll 4
    for (int i = 0; i < 16; ++i) {
      int flat = i * 256 + t;
      int c = flat >> 6, vv = flat & 63;
      ldsv[flat] = bf2f(vbuf[(trow + c) * VDIM + h * DVc + vt * 64 + vv]);
    }
    __syncthreads();
    if (t < DKc) {  // per-kd cumsum over chunk positions
      float run = 0.f;
      for (int c = 0; c < CHUNKc; ++c) {
        run += ldsg[c * DKc + t];
        ldsg[c * DKc + t] = run;
      }
      blast[t] = run;
      cdec[t] = expf(run);
    }
    __syncthreads();
#pragma unroll 4
    for (int i = 0; i < 32; ++i) {  // k * exp(blast - b) in place
      int flat = i * 256 + t;
      int c = flat >> 7, kd = flat & 127;
      float bb = ldsg[flat];
      float kv = bf2f(kbuf[(trow + c) * KDIM + h * DKc + kd]);
      ldsg[flat] = kv * expf(blast[kd] - bb);
    }
    __syncthreads();
    float d[4];
#pragma unroll
    for (int i = 0; i < 4; ++i) d[i] = cdec[k0 + i];
#pragma unroll
    for (int i = 0; i < 4; ++i)
#pragma unroll
      for (int j = 0; j < 8; ++j) S[i][j] *= d[i];
    for (int c = 0; c < CHUNKc; ++c) {
      float4 kk = *(const float4*)(ldsg + c * DKc + k0);
      float4 va = *(const float4*)(ldsv + c * 64 + v0);
      float4 vb = *(const float4*)(ldsv + c * 64 + v0 + 4);
      float kv4[4] = {kk.x, kk.y, kk.z, kk.w};
      float vv8[8] = {va.x, va.y, va.z, va.w, vb.x, vb.y, vb.z, vb.w};
#pragma unroll
      for (int i = 0; i < 4; ++i)
#pragma unroll
        for (int j = 0; j < 8; ++j) S[i][j] = fmaf(kv4[i], vv8[j], S[i][j]);
    }
  }

#pragma unroll
  for (int i = 0; i < 4; ++i)
#pragma unroll
    for (int j = 0; j < 8; ++j)
      out[sbase + (size_t)(k0 + i) * DVc + v0 + j] = S[i][j];
}

extern "C" void kernel_launch(void* const* d_in, const int* in_sizes, int n_in,
                              void* d_out, int out_size, void* d_ws, size_t ws_size,
                              hipStream_t stream) {
  const float* seg = (const float*)d_in[0];
  const float* norm_w = (const float*)d_in[1];
  const float* Wk = (const float*)d_in[2];
  const float* Wv = (const float*)d_in[3];
  const float* Wg1 = (const float*)d_in[4];
  const float* Wg2 = (const float*)d_in[5];
  const float* bg2 = (const float*)d_in[6];
  const float* S0 = (const float*)d_in[7];
  float* out = (float*)d_out;

  // ---- workspace: 84 MiB total, lifetime-aliased ----
  // region X (32 MiB): xb bf16 [8192][2048]   -> later gkbuf f32 [8192][1024]
  // region K (16 MiB): head 8 MiB = WvT bf16 [2048][2048] (dead after gemm-v),
  //                    then kb  bf16 [8192][1024]
  // region V (32 MiB): vb bf16 [8192][2048]
  // region G ( 4 MiB): WkT bf16 [1024][2048] (dead after gemm-k),
  //                    then g1buf f32 [8192][128]
  // WgT bf16 [128][2048] (0.5 MiB) lives in d_out (scan rewrites all of d_out).
  char* ws = (char*)d_ws;
  char* regX = ws;                 ws += (size_t)32 * 1024 * 1024;
  char* regK = ws;                 ws += (size_t)16 * 1024 * 1024;
  char* regV = ws;                 ws += (size_t)32 * 1024 * 1024;
  char* regG = ws;                 ws += (size_t)4 * 1024 * 1024;

  ushort* xb = (ushort*)regX;
  float* gkbuf = (float*)regX;
  ushort* WvT = (ushort*)regK;
  ushort* kb = (ushort*)regK;
  ushort* vb = (ushort*)regV;
  ushort* WkT = (ushort*)regG;
  float* g1buf = (float*)regG;
  ushort* WgT = (ushort*)d_out;

  rmsnorm_kernel<<<Mrows, 256, 0, stream>>>(seg, norm_w, xb);
  transpose_cast_kernel<<<dim3(64, 64), 256, 0, stream>>>(Wv, WvT, VDIM, VDIM);
  transpose_cast_kernel<<<dim3(64, 32), 256, 0, stream>>>(Wk, WkT, KDIM, KDIM);
  transpose_cast_kernel<<<dim3(64, 4), 256, 0, stream>>>(Wg1, WgT, 16, 128);

  // order matters for aliasing: v first (frees WvT region for kb),
  // then k (frees WkT region for g1buf), then g1.
  gemm_kernel<true><<<dim3(64, 16), 256, 0, stream>>>(xb, WvT, vb, VDIM, Dd);
  gemm_kernel<true><<<dim3(64, 8), 256, 0, stream>>>(xb, WkT, kb, KDIM, Dd);
  gemm_kernel<false><<<dim3(64, 1), 256, 0, stream>>>(xb, WgT, g1buf, 128, Dd);

  gate_kernel<<<(Mrows * KDIM) / 256, 256, 0, stream>>>(g1buf, Wg2, bg2, gkbuf);
  scan_kernel<<<dim3(4, 32), 256, 0, stream>>>(kb, vb, gkbuf, S0, out);
}

// Round 4
// 505.295 us; speedup vs baseline: 1.3895x; 1.3895x over previous
//
#include <hip/hip_runtime.h>
#include <math.h>

#define Hh 8
#define DKc 128
#define DVc 256
#define CHUNKc 64
#define GLNf 16.0f
#define EPSf 1e-5f

#define Bb 4
#define Tt 2048
#define Dd 2048
#define KDIM 1024
#define VDIM 2048
#define Mrows 8192
#define NCHUNK 32
#define NBH 32

typedef short bf16x8 __attribute__((ext_vector_type(8)));
typedef float f32x4 __attribute__((ext_vector_type(4)));
typedef ushort ushort8v __attribute__((ext_vector_type(8)));

__device__ inline ushort f2bf(float f) {
  unsigned u = __float_as_uint(f);
  unsigned r = (u + 0x7fffu + ((u >> 16) & 1u)) >> 16;
  return (ushort)r;
}
__device__ inline float bf2f(ushort u) {
  return __uint_as_float(((unsigned)u) << 16);
}
__device__ inline float logsig(float g) {
  return (g >= 0.f) ? -log1pf(expf(-g)) : g - log1pf(expf(g));
}

// ---------------- RMSNorm + bf16 cast: one block per row ----------------
__global__ __launch_bounds__(256) void rmsnorm_kernel(const float* __restrict__ seg,
                                                      const float* __restrict__ norm_w,
                                                      ushort* __restrict__ xb) {
  int row = blockIdx.x;
  int t = threadIdx.x;
  const float4* p = (const float4*)(seg + (size_t)row * Dd);
  float4 a = p[t];
  float4 b = p[t + 256];
  float ss = a.x * a.x + a.y * a.y + a.z * a.z + a.w * a.w +
             b.x * b.x + b.y * b.y + b.z * b.z + b.w * b.w;
#pragma unroll
  for (int off = 32; off > 0; off >>= 1) ss += __shfl_down(ss, off);
  __shared__ float red[4];
  if ((t & 63) == 0) red[t >> 6] = ss;
  __syncthreads();
  float tot = red[0] + red[1] + red[2] + red[3];
  float scale = rsqrtf(tot * (1.0f / (float)Dd) + EPSf);
  const float4* w4 = (const float4*)norm_w;
  float4 wa = w4[t], wb = w4[t + 256];
  ushort4 oa, ob;
  oa.x = f2bf(a.x * scale * wa.x);
  oa.y = f2bf(a.y * scale * wa.y);
  oa.z = f2bf(a.z * scale * wa.z);
  oa.w = f2bf(a.w * scale * wa.w);
  ob.x = f2bf(b.x * scale * wb.x);
  ob.y = f2bf(b.y * scale * wb.y);
  ob.z = f2bf(b.z * scale * wb.z);
  ob.w = f2bf(b.w * scale * wb.w);
  ushort4* o4 = (ushort4*)(xb + (size_t)row * Dd);
  o4[t] = oa;
  o4[t + 256] = ob;
}

// --- transpose fp32 [2048][Nstride] cols [nbase,nbase+32*gridY) -> bf16 [nloc][2048] ---
__global__ __launch_bounds__(256) void transpose_cast_kernel(const float* __restrict__ in,
                                                             ushort* __restrict__ out,
                                                             int N, int Nstride, int nbase) {
  const int K = 2048;
  __shared__ float tile[32][33];
  int k0 = blockIdx.x * 32;
  int nloc0 = blockIdx.y * 32;
  int tx = threadIdx.x & 31;
  int ty = threadIdx.x >> 5;  // 0..7
#pragma unroll
  for (int i = 0; i < 32; i += 8) {
    int k = k0 + ty + i;
    int n = nbase + nloc0 + tx;
    float v = (n < N) ? in[(size_t)k * Nstride + n] : 0.0f;
    tile[ty + i][tx] = v;
  }
  __syncthreads();
#pragma unroll
  for (int i = 0; i < 32; i += 8) {
    int nloc = nloc0 + ty + i;
    int k = k0 + tx;
    out[(size_t)nloc * K + k] = f2bf(tile[tx][ty + i]);
  }
}

// ------------- bf16 MFMA GEMM: C[M][N] = A[M][K] * Bt[N][K]^T  (m97-style) -------------
// MODE 0: fp32 C[M][N].  MODE 1: bf16 C[M][N].  MODE 2: bf16 transposed vT[bh][vv][t].
// bnOff: global bn = blockIdx.y + bnOff; Bt buffer holds rows starting at bnOff*128.
template <int MODE>
__global__ __launch_bounds__(256) void gemm_kernel(const ushort* __restrict__ A,
                                                   const ushort* __restrict__ Bt,
                                                   void* __restrict__ Cv,
                                                   int N, int K, int bnOff) {
  __shared__ __align__(16) ushort As[128 * 32];
  __shared__ __align__(16) ushort Bs[128 * 32];
  int bm = blockIdx.x;
  int bn = blockIdx.y + bnOff;
  int wave = threadIdx.x >> 6;
  int lane = threadIdx.x & 63;
  int wm = wave >> 1, wn = wave & 1;
  int lrow = lane & 15;
  int quad = lane >> 4;
  int rowInChunk = lane >> 2;      // 0..15
  int kElem = (lane & 3) * 8;      // 0,8,16,24

  f32x4 acc[4][4] = {};
  const size_t Kz = (size_t)K;

  for (int kk = 0; kk < K; kk += 32) {
#pragma unroll
    for (int r = 0; r < 2; ++r) {
      int chunk = wave * 2 + r;  // 0..7
      int arow = chunk * 16 + rowInChunk;
      const ushort* ga = A + ((size_t)(bm * 128 + arow)) * Kz + kk + kElem;
      const ushort* gb = Bt + ((size_t)(blockIdx.y * 128 + arow)) * Kz + kk + kElem;
      __builtin_amdgcn_global_load_lds((__attribute__((address_space(1))) void*)ga,
                                       (__attribute__((address_space(3))) void*)(As + chunk * 512),
                                       16, 0, 0);
      __builtin_amdgcn_global_load_lds((__attribute__((address_space(1))) void*)gb,
                                       (__attribute__((address_space(3))) void*)(Bs + chunk * 512),
                                       16, 0, 0);
    }
    __syncthreads();
    bf16x8 af[4], bfr[4];
#pragma unroll
    for (int i = 0; i < 4; ++i) {
      int r = wm * 64 + i * 16 + lrow;
      af[i] = *(const bf16x8*)(As + r * 32 + quad * 8);
    }
#pragma unroll
    for (int j = 0; j < 4; ++j) {
      int r = wn * 64 + j * 16 + lrow;
      bfr[j] = *(const bf16x8*)(Bs + r * 32 + quad * 8);
    }
#pragma unroll
    for (int i = 0; i < 4; ++i)
#pragma unroll
      for (int j = 0; j < 4; ++j)
        acc[i][j] = __builtin_amdgcn_mfma_f32_16x16x32_bf16(af[i], bfr[j], acc[i][j], 0, 0, 0);
    __syncthreads();
  }

#pragma unroll
  for (int i = 0; i < 4; ++i) {
    int m0 = bm * 128 + wm * 64 + i * 16 + quad * 4;  // rows m0..m0+3
#pragma unroll
    for (int j = 0; j < 4; ++j) {
      int col = bn * 128 + wn * 64 + j * 16 + lrow;
      if (MODE == 0) {
#pragma unroll
        for (int rg = 0; rg < 4; ++rg)
          ((float*)Cv)[(size_t)(m0 + rg) * N + col] = acc[i][j][rg];
      } else if (MODE == 1) {
#pragma unroll
        for (int rg = 0; rg < 4; ++rg)
          ((ushort*)Cv)[(size_t)(m0 + rg) * N + col] = f2bf(acc[i][j][rg]);
      } else {
        // vT[bh][vv][tloc]: b=m>>11, tloc=m&2047 (m0..m0+3 same b), h=col>>8, vv=col&255
        int b = m0 >> 11, tloc = m0 & 2047;
        int h = col >> 8, vv = col & 255;
        ushort4 o;
        o.x = f2bf(acc[i][j][0]);
        o.y = f2bf(acc[i][j][1]);
        o.z = f2bf(acc[i][j][2]);
        o.w = f2bf(acc[i][j][3]);
        *(ushort4*)((ushort*)Cv + ((size_t)((b * 8 + h) * 256 + vv)) * 2048 + tloc) = o;
      }
    }
  }
}

// ------------- chunk gate sums: L[bh][n][kd] = sum_c logsig(g1@Wg2col + b)/GLN -------------
__global__ __launch_bounds__(128) void chunksum_kernel(const float* __restrict__ g1,
                                                       const float* __restrict__ Wg2,
                                                       const float* __restrict__ bg2,
                                                       float* __restrict__ L) {
  int n = blockIdx.x, bh = blockIdx.y;
  int b = bh >> 3, h = bh & 7;
  int t = threadIdx.x;  // kd
  int kdg = h * DKc + t;
  int trow = b * Tt + n * CHUNKc;
  __shared__ float g1s[CHUNKc * 16];
#pragma unroll
  for (int i = 0; i < 8; ++i) {
    int flat = i * 128 + t;
    int c = flat >> 4, r = flat & 15;
    g1s[flat] = g1[(size_t)(trow + c) * 128 + r];
  }
  float wc[16];
#pragma unroll
  for (int r = 0; r < 16; ++r) wc[r] = Wg2[r * KDIM + kdg];
  float bias = bg2[kdg];
  __syncthreads();
  float sum = 0.f;
  for (int c = 0; c < CHUNKc; ++c) {
    float dot = bias;
#pragma unroll
    for (int r = 0; r < 16; ++r) dot = fmaf(g1s[c * 16 + r], wc[r], dot);
    sum += logsig(dot) * (1.0f / GLNf);
  }
  L[((size_t)bh * NCHUNK + n) * DKc + t] = sum;
}

// ------------- weights: kwT[bh][kd][t] = bf16(k_t * exp(Btot - B_t)); eBtot -------------
__global__ __launch_bounds__(128) void weight_kernel(const float* __restrict__ g1,
                                                     const float* __restrict__ Wg2,
                                                     const float* __restrict__ bg2,
                                                     const ushort* __restrict__ kb,
                                                     const float* __restrict__ L,
                                                     ushort* __restrict__ kwT,
                                                     float* __restrict__ eBtot) {
  int n = blockIdx.x, bh = blockIdx.y;
  int b = bh >> 3, h = bh & 7;
  int t = threadIdx.x;  // kd
  int kdg = h * DKc + t;
  int trow = b * Tt + n * CHUNKc;
  __shared__ float g1s[CHUNKc * 16];
#pragma unroll
  for (int i = 0; i < 8; ++i) {
    int flat = i * 128 + t;
    int c = flat >> 4, r = flat & 15;
    g1s[flat] = g1[(size_t)(trow + c) * 128 + r];
  }
  float wc[16];
#pragma unroll
  for (int r = 0; r < 16; ++r) wc[r] = Wg2[r * KDIM + kdg];
  float bias = bg2[kdg];

  float suffix = 0.f, Ln = 0.f, Btot = 0.f;
#pragma unroll
  for (int m = 0; m < NCHUNK; ++m) {
    float Lm = L[((size_t)bh * NCHUNK + m) * DKc + t];
    if (m > n) suffix += Lm;
    if (m == n) Ln = Lm;
    Btot += Lm;
  }
  if (n == 0) eBtot[bh * DKc + t] = expf(Btot);
  __syncthreads();

  float run = 0.f;
  size_t obase = ((size_t)bh * DKc + t) * (size_t)Tt + (size_t)n * CHUNKc;
  for (int cg = 0; cg < 8; ++cg) {
    ushort8v kw8;
#pragma unroll
    for (int j = 0; j < 8; ++j) {
      int c = cg * 8 + j;
      float dot = bias;
#pragma unroll
      for (int r = 0; r < 16; ++r) dot = fmaf(g1s[c * 16 + r], wc[r], dot);
      run += logsig(dot) * (1.0f / GLNf);
      float w = expf(suffix + Ln - run);  // exponent <= 0 always
      float kv = bf2f(kb[(size_t)(trow + c) * KDIM + kdg]);
      kw8[j] = f2bf(kv * w);
    }
    *(ushort8v*)(kwT + obase + cg * 8) = kw8;
  }
}

// ------------- S_part[ks][bh] = kwT[bh](128 x Kslice) @ vT[bh](Kslice x 256)^T -------------
__global__ __launch_bounds__(256) void kv_gemm_kernel(const ushort* __restrict__ kwT,
                                                      const ushort* __restrict__ vT,
                                                      float* __restrict__ Spart) {
  __shared__ __align__(16) ushort As[128 * 32];
  __shared__ __align__(16) ushort Bs[128 * 32];
  int bn = blockIdx.x;  // vv tile 0..1
  int bh = blockIdx.y;  // 0..31
  int ks = blockIdx.z;  // split-K 0..3
  const ushort* A = kwT + (size_t)bh * DKc * Tt;
  const ushort* B = vT + (size_t)(bh * DVc + bn * 128) * Tt;
  int wave = threadIdx.x >> 6;
  int lane = threadIdx.x & 63;
  int wm = wave >> 1, wn = wave & 1;
  int lrow = lane & 15;
  int quad = lane >> 4;
  int rowInChunk = lane >> 2;
  int kElem = (lane & 3) * 8;

  f32x4 acc[4][4] = {};
  int kk0 = ks * 512;
  for (int kk = kk0; kk < kk0 + 512; kk += 32) {
#pragma unroll
    for (int r = 0; r < 2; ++r) {
      int chunk = wave * 2 + r;
      int arow = chunk * 16 + rowInChunk;
      const ushort* ga = A + (size_t)arow * Tt + kk + kElem;
      const ushort* gb = B + (size_t)arow * Tt + kk + kElem;
      __builtin_amdgcn_global_load_lds((__attribute__((address_space(1))) void*)ga,
                                       (__attribute__((address_space(3))) void*)(As + chunk * 512),
                                       16, 0, 0);
      __builtin_amdgcn_global_load_lds((__attribute__((address_space(1))) void*)gb,
                                       (__attribute__((address_space(3))) void*)(Bs + chunk * 512),
                                       16, 0, 0);
    }
    __syncthreads();
    bf16x8 af[4], bfr[4];
#pragma unroll
    for (int i = 0; i < 4; ++i) af[i] = *(const bf16x8*)(As + (wm * 64 + i * 16 + lrow) * 32 + quad * 8);
#pragma unroll
    for (int j = 0; j < 4; ++j) bfr[j] = *(const bf16x8*)(Bs + (wn * 64 + j * 16 + lrow) * 32 + quad * 8);
#pragma unroll
    for (int i = 0; i < 4; ++i)
#pragma unroll
      for (int j = 0; j < 4; ++j)
        acc[i][j] = __builtin_amdgcn_mfma_f32_16x16x32_bf16(af[i], bfr[j], acc[i][j], 0, 0, 0);
    __syncthreads();
  }

  float* Sp = Spart + ((size_t)ks * NBH + bh) * (DKc * DVc);
#pragma unroll
  for (int i = 0; i < 4; ++i) {
    int row0 = wm * 64 + i * 16 + quad * 4;  // kd
#pragma unroll
    for (int j = 0; j < 4; ++j) {
      int col = bn * 128 + wn * 64 + j * 16 + lrow;  // vv
#pragma unroll
      for (int rg = 0; rg < 4; ++rg)
        Sp[(size_t)(row0 + rg) * DVc + col] = acc[i][j][rg];
    }
  }
}

// ------------- out = S0*eBtot + sum_ks Spart -------------
__global__ __launch_bounds__(256) void reduce_kernel(const float* __restrict__ Spart,
                                                     const float* __restrict__ eBtot,
                                                     const float* __restrict__ S0,
                                                     float* __restrict__ out) {
  int i4 = blockIdx.x * 256 + threadIdx.x;  // 0..262143 (float4 index)
  int idx = i4 * 4;
  int bh = idx >> 15;
  int kd = (idx >> 8) & 127;
  float e = eBtot[bh * DKc + kd];
  float4 a = ((const float4*)S0)[i4];
  float4 p0 = ((const float4*)Spart)[i4];
  float4 p1 = ((const float4*)Spart)[i4 + 262144];
  float4 p2 = ((const float4*)Spart)[i4 + 524288];
  float4 p3 = ((const float4*)Spart)[i4 + 786432];
  float4 r;
  r.x = a.x * e + p0.x + p1.x + p2.x + p3.x;
  r.y = a.y * e + p0.y + p1.y + p2.y + p3.y;
  r.z = a.z * e + p0.z + p1.z + p2.z + p3.z;
  r.w = a.w * e + p0.w + p1.w + p2.w + p3.w;
  ((float4*)out)[i4] = r;
}

extern "C" void kernel_launch(void* const* d_in, const int* in_sizes, int n_in,
                              void* d_out, int out_size, void* d_ws, size_t ws_size,
                              hipStream_t stream) {
  const float* seg = (const float*)d_in[0];
  const float* norm_w = (const float*)d_in[1];
  const float* Wk = (const float*)d_in[2];
  const float* Wv = (const float*)d_in[3];
  const float* Wg1 = (const float*)d_in[4];
  const float* Wg2 = (const float*)d_in[5];
  const float* bg2 = (const float*)d_in[6];
  const float* S0 = (const float*)d_in[7];
  float* out = (float*)d_out;

  // ---- workspace 84 MiB + 16 KiB, lifetime-aliased (proven-safe envelope) ----
  // regA 32 MiB: xb bf16[8192][2048] -> (xb dead after g1 gemm) kwT(16M) + Spart(16M)
  // regB 32 MiB: vT bf16[32][256][2048]  (FULL 32 MiB — the R3 bug was sizing this 16)
  // regD 16 MiB: kb bf16[8192][1024]
  // regC  4 MiB: WvT half [1024][2048] -> WkT [1024][2048] -> g1buf f32[8192][128]
  // d_out scratch: WgT bf16[128][2048] @0, Lbuf f32[32][32][128] @2MiB (both dead
  //                before reduce_kernel rewrites all of d_out)
  char* ws = (char*)d_ws;
  char* regA = ws;
  char* regB = ws + (size_t)32 * 1024 * 1024;
  char* regD = ws + (size_t)64 * 1024 * 1024;
  char* regC = ws + (size_t)80 * 1024 * 1024;
  float* eBtot = (float*)(ws + (size_t)84 * 1024 * 1024);  // 16 KiB

  ushort* xb = (ushort*)regA;
  ushort* kwT = (ushort*)regA;                 // after xb dead
  float* Spart = (float*)(regA + 16777216);    // after xb dead
  ushort* vT = (ushort*)regB;
  ushort* kb = (ushort*)regD;
  ushort* WvTh = (ushort*)regC;                // half of Wv^T at a time
  ushort* WkT = (ushort*)regC;                 // after v-gemms
  float* g1buf = (float*)regC;                 // after k-gemm (WkT dead)
  ushort* WgT = (ushort*)d_out;
  float* Lbuf = (float*)((char*)d_out + 2097152);

  rmsnorm_kernel<<<Mrows, 256, 0, stream>>>(seg, norm_w, xb);

  // v GEMM in two halves so Wv^T only ever occupies 4 MiB
  transpose_cast_kernel<<<dim3(64, 32), 256, 0, stream>>>(Wv, WvTh, VDIM, VDIM, 0);
  gemm_kernel<2><<<dim3(64, 8), 256, 0, stream>>>(xb, WvTh, vT, VDIM, Dd, 0);
  transpose_cast_kernel<<<dim3(64, 32), 256, 0, stream>>>(Wv, WvTh, VDIM, VDIM, 1024);
  gemm_kernel<2><<<dim3(64, 8), 256, 0, stream>>>(xb, WvTh, vT, VDIM, Dd, 8);

  // k GEMM (WvTh dead -> WkT)
  transpose_cast_kernel<<<dim3(64, 32), 256, 0, stream>>>(Wk, WkT, KDIM, KDIM, 0);
  gemm_kernel<1><<<dim3(64, 8), 256, 0, stream>>>(xb, WkT, kb, KDIM, Dd, 0);

  // g1 GEMM (WkT dead -> g1buf; WgT in d_out)
  transpose_cast_kernel<<<dim3(64, 4), 256, 0, stream>>>(Wg1, WgT, 16, 16, 0);
  gemm_kernel<0><<<dim3(64, 1), 256, 0, stream>>>(xb, WgT, g1buf, 128, Dd, 0);

  chunksum_kernel<<<dim3(NCHUNK, NBH), 128, 0, stream>>>(g1buf, Wg2, bg2, Lbuf);
  weight_kernel<<<dim3(NCHUNK, NBH), 128, 0, stream>>>(g1buf, Wg2, bg2, kb, Lbuf, kwT, eBtot);
  kv_gemm_kernel<<<dim3(2, NBH, 4), 256, 0, stream>>>(kwT, vT, Spart);
  reduce_kernel<<<1024, 256, 0, stream>>>(Spart, eBtot, S0, out);
}

// Round 5
// 398.222 us; speedup vs baseline: 1.7631x; 1.2689x over previous
//
#include <hip/hip_runtime.h>
#include <math.h>

#define Hh 8
#define DKc 128
#define DVc 256
#define CHUNKc 64
#define GLNf 16.0f
#define EPSf 1e-5f

#define Bb 4
#define Tt 2048
#define Dd 2048
#define KDIM 1024
#define VDIM 2048
#define Mrows 8192
#define NCHUNK 32
#define NBH 32

typedef short bf16x8 __attribute__((ext_vector_type(8)));
typedef float f32x4 __attribute__((ext_vector_type(4)));
typedef ushort ushort8v __attribute__((ext_vector_type(8)));

__device__ inline ushort f2bf(float f) {
  unsigned u = __float_as_uint(f);
  unsigned r = (u + 0x7fffu + ((u >> 16) & 1u)) >> 16;
  return (ushort)r;
}
__device__ inline float bf2f(ushort u) {
  return __uint_as_float(((unsigned)u) << 16);
}
// log_sigmoid(g) = min(g,0) - log(1 + exp(-|g|)); branch-free, hw v_exp/v_log.
// (identical to the piecewise form: both cases reduce to this expression)
__device__ inline float logsig(float g) {
  return fminf(g, 0.f) - __logf(1.f + __expf(-fabsf(g)));
}

// ---------------- RMSNorm + bf16 cast: one block per row ----------------
__global__ __launch_bounds__(256) void rmsnorm_kernel(const float* __restrict__ seg,
                                                      const float* __restrict__ norm_w,
                                                      ushort* __restrict__ xb) {
  int row = blockIdx.x;
  int t = threadIdx.x;
  const float4* p = (const float4*)(seg + (size_t)row * Dd);
  float4 a = p[t];
  float4 b = p[t + 256];
  float ss = a.x * a.x + a.y * a.y + a.z * a.z + a.w * a.w +
             b.x * b.x + b.y * b.y + b.z * b.z + b.w * b.w;
#pragma unroll
  for (int off = 32; off > 0; off >>= 1) ss += __shfl_down(ss, off);
  __shared__ float red[4];
  if ((t & 63) == 0) red[t >> 6] = ss;
  __syncthreads();
  float tot = red[0] + red[1] + red[2] + red[3];
  float scale = rsqrtf(tot * (1.0f / (float)Dd) + EPSf);
  const float4* w4 = (const float4*)norm_w;
  float4 wa = w4[t], wb = w4[t + 256];
  ushort4 oa, ob;
  oa.x = f2bf(a.x * scale * wa.x);
  oa.y = f2bf(a.y * scale * wa.y);
  oa.z = f2bf(a.z * scale * wa.z);
  oa.w = f2bf(a.w * scale * wa.w);
  ob.x = f2bf(b.x * scale * wb.x);
  ob.y = f2bf(b.y * scale * wb.y);
  ob.z = f2bf(b.z * scale * wb.z);
  ob.w = f2bf(b.w * scale * wb.w);
  ushort4* o4 = (ushort4*)(xb + (size_t)row * Dd);
  o4[t] = oa;
  o4[t + 256] = ob;
}

// --- transpose fp32 [2048][Nstride] cols [nbase,nbase+32*gridY) -> bf16 [nloc][2048] ---
__global__ __launch_bounds__(256) void transpose_cast_kernel(const float* __restrict__ in,
                                                             ushort* __restrict__ out,
                                                             int N, int Nstride, int nbase) {
  const int K = 2048;
  __shared__ float tile[32][33];
  int k0 = blockIdx.x * 32;
  int nloc0 = blockIdx.y * 32;
  int tx = threadIdx.x & 31;
  int ty = threadIdx.x >> 5;  // 0..7
#pragma unroll
  for (int i = 0; i < 32; i += 8) {
    int k = k0 + ty + i;
    int n = nbase + nloc0 + tx;
    float v = (n < N) ? in[(size_t)k * Nstride + n] : 0.0f;
    tile[ty + i][tx] = v;
  }
  __syncthreads();
#pragma unroll
  for (int i = 0; i < 32; i += 8) {
    int nloc = nloc0 + ty + i;
    int k = k0 + tx;
    out[(size_t)nloc * K + k] = f2bf(tile[tx][ty + i]);
  }
}

// ------------- bf16 MFMA GEMM: C[M][N] = A[M][K] * Bt[N][K]^T  (m97-style) -------------
// MODE 0: fp32 C[M][N].  MODE 1: bf16 C[M][N].  MODE 2: bf16 transposed vT[bh][vv][t].
// bnOff: global bn = blockIdx.y + bnOff; Bt buffer holds rows starting at bnOff*128.
template <int MODE>
__global__ __launch_bounds__(256) void gemm_kernel(const ushort* __restrict__ A,
                                                   const ushort* __restrict__ Bt,
                                                   void* __restrict__ Cv,
                                                   int N, int K, int bnOff) {
  __shared__ __align__(16) ushort As[128 * 32];
  __shared__ __align__(16) ushort Bs[128 * 32];
  int bm = blockIdx.x;
  int bn = blockIdx.y + bnOff;
  int wave = threadIdx.x >> 6;
  int lane = threadIdx.x & 63;
  int wm = wave >> 1, wn = wave & 1;
  int lrow = lane & 15;
  int quad = lane >> 4;
  int rowInChunk = lane >> 2;      // 0..15
  int kElem = (lane & 3) * 8;      // 0,8,16,24

  f32x4 acc[4][4] = {};
  const size_t Kz = (size_t)K;

  for (int kk = 0; kk < K; kk += 32) {
#pragma unroll
    for (int r = 0; r < 2; ++r) {
      int chunk = wave * 2 + r;  // 0..7
      int arow = chunk * 16 + rowInChunk;
      const ushort* ga = A + ((size_t)(bm * 128 + arow)) * Kz + kk + kElem;
      const ushort* gb = Bt + ((size_t)(blockIdx.y * 128 + arow)) * Kz + kk + kElem;
      __builtin_amdgcn_global_load_lds((__attribute__((address_space(1))) void*)ga,
                                       (__attribute__((address_space(3))) void*)(As + chunk * 512),
                                       16, 0, 0);
      __builtin_amdgcn_global_load_lds((__attribute__((address_space(1))) void*)gb,
                                       (__attribute__((address_space(3))) void*)(Bs + chunk * 512),
                                       16, 0, 0);
    }
    __syncthreads();
    bf16x8 af[4], bfr[4];
#pragma unroll
    for (int i = 0; i < 4; ++i) {
      int r = wm * 64 + i * 16 + lrow;
      af[i] = *(const bf16x8*)(As + r * 32 + quad * 8);
    }
#pragma unroll
    for (int j = 0; j < 4; ++j) {
      int r = wn * 64 + j * 16 + lrow;
      bfr[j] = *(const bf16x8*)(Bs + r * 32 + quad * 8);
    }
#pragma unroll
    for (int i = 0; i < 4; ++i)
#pragma unroll
      for (int j = 0; j < 4; ++j)
        acc[i][j] = __builtin_amdgcn_mfma_f32_16x16x32_bf16(af[i], bfr[j], acc[i][j], 0, 0, 0);
    __syncthreads();
  }

#pragma unroll
  for (int i = 0; i < 4; ++i) {
    int m0 = bm * 128 + wm * 64 + i * 16 + quad * 4;  // rows m0..m0+3
#pragma unroll
    for (int j = 0; j < 4; ++j) {
      int col = bn * 128 + wn * 64 + j * 16 + lrow;
      if (MODE == 0) {
#pragma unroll
        for (int rg = 0; rg < 4; ++rg)
          ((float*)Cv)[(size_t)(m0 + rg) * N + col] = acc[i][j][rg];
      } else if (MODE == 1) {
#pragma unroll
        for (int rg = 0; rg < 4; ++rg)
          ((ushort*)Cv)[(size_t)(m0 + rg) * N + col] = f2bf(acc[i][j][rg]);
      } else {
        // vT[bh][vv][tloc]: b=m>>11, tloc=m&2047 (m0..m0+3 same b), h=col>>8, vv=col&255
        int b = m0 >> 11, tloc = m0 & 2047;
        int h = col >> 8, vv = col & 255;
        ushort4 o;
        o.x = f2bf(acc[i][j][0]);
        o.y = f2bf(acc[i][j][1]);
        o.z = f2bf(acc[i][j][2]);
        o.w = f2bf(acc[i][j][3]);
        *(ushort4*)((ushort*)Cv + ((size_t)((b * 8 + h) * 256 + vv)) * 2048 + tloc) = o;
      }
    }
  }
}

// ------------- chunk gate sums: L[bh][n][kd] = sum_c logsig(g1@Wg2col + b)/GLN -------------
__global__ __launch_bounds__(128) void chunksum_kernel(const float* __restrict__ g1,
                                                       const float* __restrict__ Wg2,
                                                       const float* __restrict__ bg2,
                                                       float* __restrict__ L) {
  int n = blockIdx.x, bh = blockIdx.y;
  int b = bh >> 3, h = bh & 7;
  int t = threadIdx.x;  // kd
  int kdg = h * DKc + t;
  int trow = b * Tt + n * CHUNKc;
  __shared__ float g1s[CHUNKc * 16];
#pragma unroll
  for (int i = 0; i < 8; ++i) {
    int flat = i * 128 + t;
    int c = flat >> 4, r = flat & 15;
    g1s[flat] = g1[(size_t)(trow + c) * 128 + r];
  }
  float wc[16];
#pragma unroll
  for (int r = 0; r < 16; ++r) wc[r] = Wg2[r * KDIM + kdg];
  float bias = bg2[kdg];
  __syncthreads();
  float sum = 0.f;
  for (int c = 0; c < CHUNKc; ++c) {
    float dot = bias;
#pragma unroll
    for (int r = 0; r < 16; ++r) dot = fmaf(g1s[c * 16 + r], wc[r], dot);
    sum += logsig(dot) * (1.0f / GLNf);
  }
  L[((size_t)bh * NCHUNK + n) * DKc + t] = sum;
}

// ------------- weights: kwT[bh][kd][t] = bf16(k_t * exp(Btot - B_t)); eBtot -------------
__global__ __launch_bounds__(128) void weight_kernel(const float* __restrict__ g1,
                                                     const float* __restrict__ Wg2,
                                                     const float* __restrict__ bg2,
                                                     const ushort* __restrict__ kb,
                                                     const float* __restrict__ L,
                                                     ushort* __restrict__ kwT,
                                                     float* __restrict__ eBtot) {
  int n = blockIdx.x, bh = blockIdx.y;
  int b = bh >> 3, h = bh & 7;
  int t = threadIdx.x;  // kd
  int kdg = h * DKc + t;
  int trow = b * Tt + n * CHUNKc;
  __shared__ float g1s[CHUNKc * 16];
#pragma unroll
  for (int i = 0; i < 8; ++i) {
    int flat = i * 128 + t;
    int c = flat >> 4, r = flat & 15;
    g1s[flat] = g1[(size_t)(trow + c) * 128 + r];
  }
  float wc[16];
#pragma unroll
  for (int r = 0; r < 16; ++r) wc[r] = Wg2[r * KDIM + kdg];
  float bias = bg2[kdg];

  float suffix = 0.f, Ln = 0.f, Btot = 0.f;
#pragma unroll
  for (int m = 0; m < NCHUNK; ++m) {
    float Lm = L[((size_t)bh * NCHUNK + m) * DKc + t];
    if (m > n) suffix += Lm;
    if (m == n) Ln = Lm;
    Btot += Lm;
  }
  if (n == 0) eBtot[bh * DKc + t] = __expf(Btot);
  __syncthreads();

  float run = 0.f;
  size_t obase = ((size_t)bh * DKc + t) * (size_t)Tt + (size_t)n * CHUNKc;
  for (int cg = 0; cg < 8; ++cg) {
    ushort8v kw8;
#pragma unroll
    for (int j = 0; j < 8; ++j) {
      int c = cg * 8 + j;
      float dot = bias;
#pragma unroll
      for (int r = 0; r < 16; ++r) dot = fmaf(g1s[c * 16 + r], wc[r], dot);
      run += logsig(dot) * (1.0f / GLNf);
      float w = __expf(suffix + Ln - run);  // exponent <= 0 always
      float kv = bf2f(kb[(size_t)(trow + c) * KDIM + kdg]);
      kw8[j] = f2bf(kv * w);
    }
    *(ushort8v*)(kwT + obase + cg * 8) = kw8;
  }
}

// ------------- S_part[ks][bh] = kwT[bh](128 x Kslice) @ vT[bh](Kslice x 256)^T -------------
__global__ __launch_bounds__(256) void kv_gemm_kernel(const ushort* __restrict__ kwT,
                                                      const ushort* __restrict__ vT,
                                                      float* __restrict__ Spart) {
  __shared__ __align__(16) ushort As[128 * 32];
  __shared__ __align__(16) ushort Bs[128 * 32];
  int bn = blockIdx.x;  // vv tile 0..1
  int bh = blockIdx.y;  // 0..31
  int ks = blockIdx.z;  // split-K 0..3
  const ushort* A = kwT + (size_t)bh * DKc * Tt;
  const ushort* B = vT + (size_t)(bh * DVc + bn * 128) * Tt;
  int wave = threadIdx.x >> 6;
  int lane = threadIdx.x & 63;
  int wm = wave >> 1, wn = wave & 1;
  int lrow = lane & 15;
  int quad = lane >> 4;
  int rowInChunk = lane >> 2;
  int kElem = (lane & 3) * 8;

  f32x4 acc[4][4] = {};
  int kk0 = ks * 512;
  for (int kk = kk0; kk < kk0 + 512; kk += 32) {
#pragma unroll
    for (int r = 0; r < 2; ++r) {
      int chunk = wave * 2 + r;
      int arow = chunk * 16 + rowInChunk;
      const ushort* ga = A + (size_t)arow * Tt + kk + kElem;
      const ushort* gb = B + (size_t)arow * Tt + kk + kElem;
      __builtin_amdgcn_global_load_lds((__attribute__((address_space(1))) void*)ga,
                                       (__attribute__((address_space(3))) void*)(As + chunk * 512),
                                       16, 0, 0);
      __builtin_amdgcn_global_load_lds((__attribute__((address_space(1))) void*)gb,
                                       (__attribute__((address_space(3))) void*)(Bs + chunk * 512),
                                       16, 0, 0);
    }
    __syncthreads();
    bf16x8 af[4], bfr[4];
#pragma unroll
    for (int i = 0; i < 4; ++i) af[i] = *(const bf16x8*)(As + (wm * 64 + i * 16 + lrow) * 32 + quad * 8);
#pragma unroll
    for (int j = 0; j < 4; ++j) bfr[j] = *(const bf16x8*)(Bs + (wn * 64 + j * 16 + lrow) * 32 + quad * 8);
#pragma unroll
    for (int i = 0; i < 4; ++i)
#pragma unroll
      for (int j = 0; j < 4; ++j)
        acc[i][j] = __builtin_amdgcn_mfma_f32_16x16x32_bf16(af[i], bfr[j], acc[i][j], 0, 0, 0);
    __syncthreads();
  }

  float* Sp = Spart + ((size_t)ks * NBH + bh) * (DKc * DVc);
#pragma unroll
  for (int i = 0; i < 4; ++i) {
    int row0 = wm * 64 + i * 16 + quad * 4;  // kd
#pragma unroll
    for (int j = 0; j < 4; ++j) {
      int col = bn * 128 + wn * 64 + j * 16 + lrow;  // vv
#pragma unroll
      for (int rg = 0; rg < 4; ++rg)
        Sp[(size_t)(row0 + rg) * DVc + col] = acc[i][j][rg];
    }
  }
}

// ------------- out = S0*eBtot + sum_ks Spart -------------
__global__ __launch_bounds__(256) void reduce_kernel(const float* __restrict__ Spart,
                                                     const float* __restrict__ eBtot,
                                                     const float* __restrict__ S0,
                                                     float* __restrict__ out) {
  int i4 = blockIdx.x * 256 + threadIdx.x;  // 0..262143 (float4 index)
  int idx = i4 * 4;
  int bh = idx >> 15;
  int kd = (idx >> 8) & 127;
  float e = eBtot[bh * DKc + kd];
  float4 a = ((const float4*)S0)[i4];
  float4 p0 = ((const float4*)Spart)[i4];
  float4 p1 = ((const float4*)Spart)[i4 + 262144];
  float4 p2 = ((const float4*)Spart)[i4 + 524288];
  float4 p3 = ((const float4*)Spart)[i4 + 786432];
  float4 r;
  r.x = a.x * e + p0.x + p1.x + p2.x + p3.x;
  r.y = a.y * e + p0.y + p1.y + p2.y + p3.y;
  r.z = a.z * e + p0.z + p1.z + p2.z + p3.z;
  r.w = a.w * e + p0.w + p1.w + p2.w + p3.w;
  ((float4*)out)[i4] = r;
}

extern "C" void kernel_launch(void* const* d_in, const int* in_sizes, int n_in,
                              void* d_out, int out_size, void* d_ws, size_t ws_size,
                              hipStream_t stream) {
  const float* seg = (const float*)d_in[0];
  const float* norm_w = (const float*)d_in[1];
  const float* Wk = (const float*)d_in[2];
  const float* Wv = (const float*)d_in[3];
  const float* Wg1 = (const float*)d_in[4];
  const float* Wg2 = (const float*)d_in[5];
  const float* bg2 = (const float*)d_in[6];
  const float* S0 = (const float*)d_in[7];
  float* out = (float*)d_out;

  // ---- workspace 84 MiB + 16 KiB, lifetime-aliased (proven-safe envelope) ----
  // regA 32 MiB: xb bf16[8192][2048] -> (xb dead after g1 gemm) kwT(16M) + Spart(16M)
  // regB 32 MiB: vT bf16[32][256][2048]
  // regD 16 MiB: kb bf16[8192][1024]
  // regC  4 MiB: WvT half [1024][2048] -> WkT [1024][2048] -> g1buf f32[8192][128]
  // d_out scratch: WgT bf16[128][2048] @0, Lbuf f32[32][32][128] @2MiB (both dead
  //                before reduce_kernel rewrites all of d_out)
  char* ws = (char*)d_ws;
  char* regA = ws;
  char* regB = ws + (size_t)32 * 1024 * 1024;
  char* regD = ws + (size_t)64 * 1024 * 1024;
  char* regC = ws + (size_t)80 * 1024 * 1024;
  float* eBtot = (float*)(ws + (size_t)84 * 1024 * 1024);  // 16 KiB

  ushort* xb = (ushort*)regA;
  ushort* kwT = (ushort*)regA;                 // after xb dead
  float* Spart = (float*)(regA + 16777216);    // after xb dead
  ushort* vT = (ushort*)regB;
  ushort* kb = (ushort*)regD;
  ushort* WvTh = (ushort*)regC;                // half of Wv^T at a time
  ushort* WkT = (ushort*)regC;                 // after v-gemms
  float* g1buf = (float*)regC;                 // after k-gemm (WkT dead)
  ushort* WgT = (ushort*)d_out;
  float* Lbuf = (float*)((char*)d_out + 2097152);

  rmsnorm_kernel<<<Mrows, 256, 0, stream>>>(seg, norm_w, xb);

  // v GEMM in two halves so Wv^T only ever occupies 4 MiB
  transpose_cast_kernel<<<dim3(64, 32), 256, 0, stream>>>(Wv, WvTh, VDIM, VDIM, 0);
  gemm_kernel<2><<<dim3(64, 8), 256, 0, stream>>>(xb, WvTh, vT, VDIM, Dd, 0);
  transpose_cast_kernel<<<dim3(64, 32), 256, 0, stream>>>(Wv, WvTh, VDIM, VDIM, 1024);
  gemm_kernel<2><<<dim3(64, 8), 256, 0, stream>>>(xb, WvTh, vT, VDIM, Dd, 8);

  // k GEMM (WvTh dead -> WkT)
  transpose_cast_kernel<<<dim3(64, 32), 256, 0, stream>>>(Wk, WkT, KDIM, KDIM, 0);
  gemm_kernel<1><<<dim3(64, 8), 256, 0, stream>>>(xb, WkT, kb, KDIM, Dd, 0);

  // g1 GEMM (WkT dead -> g1buf; WgT in d_out)
  transpose_cast_kernel<<<dim3(64, 4), 256, 0, stream>>>(Wg1, WgT, 16, 16, 0);
  gemm_kernel<0><<<dim3(64, 1), 256, 0, stream>>>(xb, WgT, g1buf, 128, Dd, 0);

  chunksum_kernel<<<dim3(NCHUNK, NBH), 128, 0, stream>>>(g1buf, Wg2, bg2, Lbuf);
  weight_kernel<<<dim3(NCHUNK, NBH), 128, 0, stream>>>(g1buf, Wg2, bg2, kb, Lbuf, kwT, eBtot);
  kv_gemm_kernel<<<dim3(2, NBH, 4), 256, 0, stream>>>(kwT, vT, Spart);
  reduce_kernel<<<1024, 256, 0, stream>>>(Spart, eBtot, S0, out);
}

// Round 6
// 376.193 us; speedup vs baseline: 1.8663x; 1.0586x over previous
//
#include <hip/hip_runtime.h>
#include <math.h>

#define Hh 8
#define DKc 128
#define DVc 256
#define CHUNKc 64
#define GLNf 16.0f
#define EPSf 1e-5f

#define Bb 4
#define Tt 2048
#define Dd 2048
#define KDIM 1024
#define VDIM 2048
#define Mrows 8192
#define NCHUNK 32
#define NBH 32

typedef short bf16x8 __attribute__((ext_vector_type(8)));
typedef float f32x4 __attribute__((ext_vector_type(4)));
typedef ushort ushort8v __attribute__((ext_vector_type(8)));

__device__ inline ushort f2bf(float f) {
  unsigned u = __float_as_uint(f);
  unsigned r = (u + 0x7fffu + ((u >> 16) & 1u)) >> 16;
  return (ushort)r;
}
__device__ inline float bf2f(ushort u) {
  return __uint_as_float(((unsigned)u) << 16);
}
// log_sigmoid(g) = min(g,0) - log(1 + exp(-|g|)); branch-free, hw v_exp/v_log.
__device__ inline float logsig(float g) {
  return fminf(g, 0.f) - __logf(1.f + __expf(-fabsf(g)));
}

// ---------------- RMSNorm + bf16 cast: one block per row ----------------
__global__ __launch_bounds__(256) void rmsnorm_kernel(const float* __restrict__ seg,
                                                      const float* __restrict__ norm_w,
                                                      ushort* __restrict__ xb) {
  int row = blockIdx.x;
  int t = threadIdx.x;
  const float4* p = (const float4*)(seg + (size_t)row * Dd);
  float4 a = p[t];
  float4 b = p[t + 256];
  float ss = a.x * a.x + a.y * a.y + a.z * a.z + a.w * a.w +
             b.x * b.x + b.y * b.y + b.z * b.z + b.w * b.w;
#pragma unroll
  for (int off = 32; off > 0; off >>= 1) ss += __shfl_down(ss, off);
  __shared__ float red[4];
  if ((t & 63) == 0) red[t >> 6] = ss;
  __syncthreads();
  float tot = red[0] + red[1] + red[2] + red[3];
  float scale = rsqrtf(tot * (1.0f / (float)Dd) + EPSf);
  const float4* w4 = (const float4*)norm_w;
  float4 wa = w4[t], wb = w4[t + 256];
  ushort4 oa, ob;
  oa.x = f2bf(a.x * scale * wa.x);
  oa.y = f2bf(a.y * scale * wa.y);
  oa.z = f2bf(a.z * scale * wa.z);
  oa.w = f2bf(a.w * scale * wa.w);
  ob.x = f2bf(b.x * scale * wb.x);
  ob.y = f2bf(b.y * scale * wb.y);
  ob.z = f2bf(b.z * scale * wb.z);
  ob.w = f2bf(b.w * scale * wb.w);
  ushort4* o4 = (ushort4*)(xb + (size_t)row * Dd);
  o4[t] = oa;
  o4[t + 256] = ob;
}

// --- transpose fp32 [2048][Nstride] cols [nbase,nbase+32*gridY) -> bf16 [nloc][2048] ---
__global__ __launch_bounds__(256) void transpose_cast_kernel(const float* __restrict__ in,
                                                             ushort* __restrict__ out,
                                                             int N, int Nstride, int nbase) {
  const int K = 2048;
  __shared__ float tile[32][33];
  int k0 = blockIdx.x * 32;
  int nloc0 = blockIdx.y * 32;
  int tx = threadIdx.x & 31;
  int ty = threadIdx.x >> 5;  // 0..7
#pragma unroll
  for (int i = 0; i < 32; i += 8) {
    int k = k0 + ty + i;
    int n = nbase + nloc0 + tx;
    float v = (n < N) ? in[(size_t)k * Nstride + n] : 0.0f;
    tile[ty + i][tx] = v;
  }
  __syncthreads();
#pragma unroll
  for (int i = 0; i < 32; i += 8) {
    int nloc = nloc0 + ty + i;
    int k = k0 + tx;
    out[(size_t)nloc * K + k] = f2bf(tile[tx][ty + i]);
  }
}

// --- fused transpose: W_allT[3200][2048] = [Wv^T(2048) ; Wk^T(1024) ; Wg1^T pad(128)] ---
__global__ __launch_bounds__(256) void transpose_all_kernel(const float* __restrict__ Wv,
                                                            const float* __restrict__ Wk,
                                                            const float* __restrict__ Wg1,
                                                            ushort* __restrict__ Wall) {
  const int K = 2048;
  __shared__ float tile[32][33];
  int k0 = blockIdx.x * 32;
  int n0 = blockIdx.y * 32;  // global output row base 0..3168
  const float* src;
  int N, stride, nb;
  if (n0 < 2048) {
    src = Wv; N = 2048; stride = 2048; nb = n0;
  } else if (n0 < 3072) {
    src = Wk; N = 1024; stride = 1024; nb = n0 - 2048;
  } else {
    src = Wg1; N = 16; stride = 16; nb = n0 - 3072;
  }
  int tx = threadIdx.x & 31;
  int ty = threadIdx.x >> 5;
#pragma unroll
  for (int i = 0; i < 32; i += 8) {
    int k = k0 + ty + i;
    int n = nb + tx;
    tile[ty + i][tx] = (n < N) ? src[(size_t)k * stride + n] : 0.0f;
  }
  __syncthreads();
#pragma unroll
  for (int i = 0; i < 32; i += 8) {
    Wall[(size_t)(n0 + ty + i) * K + k0 + tx] = f2bf(tile[tx][ty + i]);
  }
}

// ------------- bf16 MFMA GEMM: C[M][N] = A[M][K] * Bt[N][K]^T  (m97-style) -------------
// MODE 0: fp32 C[M][N].  MODE 1: bf16 C[M][N].  MODE 2: bf16 transposed vT[bh][vv][t].
template <int MODE>
__global__ __launch_bounds__(256) void gemm_kernel(const ushort* __restrict__ A,
                                                   const ushort* __restrict__ Bt,
                                                   void* __restrict__ Cv,
                                                   int N, int K, int bnOff) {
  __shared__ __align__(16) ushort As[128 * 32];
  __shared__ __align__(16) ushort Bs[128 * 32];
  int bm = blockIdx.x;
  int bn = blockIdx.y + bnOff;
  int wave = threadIdx.x >> 6;
  int lane = threadIdx.x & 63;
  int wm = wave >> 1, wn = wave & 1;
  int lrow = lane & 15;
  int quad = lane >> 4;
  int rowInChunk = lane >> 2;      // 0..15
  int kElem = (lane & 3) * 8;      // 0,8,16,24

  f32x4 acc[4][4] = {};
  const size_t Kz = (size_t)K;

  for (int kk = 0; kk < K; kk += 32) {
#pragma unroll
    for (int r = 0; r < 2; ++r) {
      int chunk = wave * 2 + r;  // 0..7
      int arow = chunk * 16 + rowInChunk;
      const ushort* ga = A + ((size_t)(bm * 128 + arow)) * Kz + kk + kElem;
      const ushort* gb = Bt + ((size_t)(blockIdx.y * 128 + arow)) * Kz + kk + kElem;
      __builtin_amdgcn_global_load_lds((__attribute__((address_space(1))) void*)ga,
                                       (__attribute__((address_space(3))) void*)(As + chunk * 512),
                                       16, 0, 0);
      __builtin_amdgcn_global_load_lds((__attribute__((address_space(1))) void*)gb,
                                       (__attribute__((address_space(3))) void*)(Bs + chunk * 512),
                                       16, 0, 0);
    }
    __syncthreads();
    bf16x8 af[4], bfr[4];
#pragma unroll
    for (int i = 0; i < 4; ++i) {
      int r = wm * 64 + i * 16 + lrow;
      af[i] = *(const bf16x8*)(As + r * 32 + quad * 8);
    }
#pragma unroll
    for (int j = 0; j < 4; ++j) {
      int r = wn * 64 + j * 16 + lrow;
      bfr[j] = *(const bf16x8*)(Bs + r * 32 + quad * 8);
    }
#pragma unroll
    for (int i = 0; i < 4; ++i)
#pragma unroll
      for (int j = 0; j < 4; ++j)
        acc[i][j] = __builtin_amdgcn_mfma_f32_16x16x32_bf16(af[i], bfr[j], acc[i][j], 0, 0, 0);
    __syncthreads();
  }

#pragma unroll
  for (int i = 0; i < 4; ++i) {
    int m0 = bm * 128 + wm * 64 + i * 16 + quad * 4;  // rows m0..m0+3
#pragma unroll
    for (int j = 0; j < 4; ++j) {
      int col = bn * 128 + wn * 64 + j * 16 + lrow;
      if (MODE == 0) {
#pragma unroll
        for (int rg = 0; rg < 4; ++rg)
          ((float*)Cv)[(size_t)(m0 + rg) * N + col] = acc[i][j][rg];
      } else if (MODE == 1) {
#pragma unroll
        for (int rg = 0; rg < 4; ++rg)
          ((ushort*)Cv)[(size_t)(m0 + rg) * N + col] = f2bf(acc[i][j][rg]);
      } else {
        int b = m0 >> 11, tloc = m0 & 2047;
        int h = col >> 8, vv = col & 255;
        ushort4 o;
        o.x = f2bf(acc[i][j][0]);
        o.y = f2bf(acc[i][j][1]);
        o.z = f2bf(acc[i][j][2]);
        o.w = f2bf(acc[i][j][3]);
        *(ushort4*)((ushort*)Cv + ((size_t)((b * 8 + h) * 256 + vv)) * 2048 + tloc) = o;
      }
    }
  }
}

// ------- fused GEMM over W_allT[3200][2048]: bn<16 -> vT, bn in[16,24) -> kT, bn==24 -> g1 -------
__global__ __launch_bounds__(256) void gemm_fused_kernel(const ushort* __restrict__ A,
                                                         const ushort* __restrict__ Wall,
                                                         ushort* __restrict__ vT,
                                                         ushort* __restrict__ kT,
                                                         float* __restrict__ g1) {
  __shared__ __align__(16) ushort As[128 * 32];
  __shared__ __align__(16) ushort Bs[128 * 32];
  int bm = blockIdx.x;
  int bn = blockIdx.y;  // 0..24
  int wave = threadIdx.x >> 6;
  int lane = threadIdx.x & 63;
  int wm = wave >> 1, wn = wave & 1;
  int lrow = lane & 15;
  int quad = lane >> 4;
  int rowInChunk = lane >> 2;
  int kElem = (lane & 3) * 8;

  f32x4 acc[4][4] = {};
  for (int kk = 0; kk < Dd; kk += 32) {
#pragma unroll
    for (int r = 0; r < 2; ++r) {
      int chunk = wave * 2 + r;
      int arow = chunk * 16 + rowInChunk;
      const ushort* ga = A + ((size_t)(bm * 128 + arow)) * Dd + kk + kElem;
      const ushort* gb = Wall + ((size_t)(bn * 128 + arow)) * Dd + kk + kElem;
      __builtin_amdgcn_global_load_lds((__attribute__((address_space(1))) void*)ga,
                                       (__attribute__((address_space(3))) void*)(As + chunk * 512),
                                       16, 0, 0);
      __builtin_amdgcn_global_load_lds((__attribute__((address_space(1))) void*)gb,
                                       (__attribute__((address_space(3))) void*)(Bs + chunk * 512),
                                       16, 0, 0);
    }
    __syncthreads();
    bf16x8 af[4], bfr[4];
#pragma unroll
    for (int i = 0; i < 4; ++i) af[i] = *(const bf16x8*)(As + (wm * 64 + i * 16 + lrow) * 32 + quad * 8);
#pragma unroll
    for (int j = 0; j < 4; ++j) bfr[j] = *(const bf16x8*)(Bs + (wn * 64 + j * 16 + lrow) * 32 + quad * 8);
#pragma unroll
    for (int i = 0; i < 4; ++i)
#pragma unroll
      for (int j = 0; j < 4; ++j)
        acc[i][j] = __builtin_amdgcn_mfma_f32_16x16x32_bf16(af[i], bfr[j], acc[i][j], 0, 0, 0);
    __syncthreads();
  }

#pragma unroll
  for (int i = 0; i < 4; ++i) {
    int m0 = bm * 128 + wm * 64 + i * 16 + quad * 4;
    int b = m0 >> 11, tloc = m0 & 2047;
#pragma unroll
    for (int j = 0; j < 4; ++j) {
      int col = bn * 128 + wn * 64 + j * 16 + lrow;
      if (bn < 16) {  // v: vT[bh][vv][t]
        int h = col >> 8, vv = col & 255;
        ushort4 o;
        o.x = f2bf(acc[i][j][0]);
        o.y = f2bf(acc[i][j][1]);
        o.z = f2bf(acc[i][j][2]);
        o.w = f2bf(acc[i][j][3]);
        *(ushort4*)(vT + ((size_t)((b * 8 + h) * 256 + vv)) * 2048 + tloc) = o;
      } else if (bn < 24) {  // k: kT[bh][kd][t]
        int ck = col - 2048;
        int h = ck >> 7, kd = ck & 127;
        ushort4 o;
        o.x = f2bf(acc[i][j][0]);
        o.y = f2bf(acc[i][j][1]);
        o.z = f2bf(acc[i][j][2]);
        o.w = f2bf(acc[i][j][3]);
        *(ushort4*)(kT + ((size_t)((b * 8 + h) * 128 + kd)) * 2048 + tloc) = o;
      } else {  // g1 fp32 [8192][128]; col-3072 in [0,128) by construction
        int cg = col - 3072;
#pragma unroll
        for (int rg = 0; rg < 4; ++rg)
          g1[(size_t)(m0 + rg) * 128 + cg] = acc[i][j][rg];
      }
    }
  }
}

// ------------- chunk gate sums: L[bh][n][kd] = sum_c logsig(g1@Wg2col + b)/GLN -------------
__global__ __launch_bounds__(128) void chunksum_kernel(const float* __restrict__ g1,
                                                       const float* __restrict__ Wg2,
                                                       const float* __restrict__ bg2,
                                                       float* __restrict__ L) {
  int n = blockIdx.x, bh = blockIdx.y;
  int b = bh >> 3, h = bh & 7;
  int t = threadIdx.x;  // kd
  int kdg = h * DKc + t;
  int trow = b * Tt + n * CHUNKc;
  __shared__ float g1s[CHUNKc * 16];
#pragma unroll
  for (int i = 0; i < 8; ++i) {
    int flat = i * 128 + t;
    int c = flat >> 4, r = flat & 15;
    g1s[flat] = g1[(size_t)(trow + c) * 128 + r];
  }
  float wc[16];
#pragma unroll
  for (int r = 0; r < 16; ++r) wc[r] = Wg2[r * KDIM + kdg];
  float bias = bg2[kdg];
  __syncthreads();
  float sum = 0.f;
  for (int c = 0; c < CHUNKc; ++c) {
    float dot = bias;
#pragma unroll
    for (int r = 0; r < 16; ++r) dot = fmaf(g1s[c * 16 + r], wc[r], dot);
    sum += logsig(dot) * (1.0f / GLNf);
  }
  L[((size_t)bh * NCHUNK + n) * DKc + t] = sum;
}

// ------------- weights: kwT[bh][kd][t] = bf16(k * exp(Btot - B_t)); eBtot -------------
// KLAY 0: k from kb [8192][1024].  KLAY 1: k read in-place from kwT (RMW).
template <int KLAY>
__global__ __launch_bounds__(128) void weight_kernel(const float* __restrict__ g1,
                                                     const float* __restrict__ Wg2,
                                                     const float* __restrict__ bg2,
                                                     const ushort* __restrict__ kb,
                                                     const float* __restrict__ L,
                                                     ushort* __restrict__ kwT,
                                                     float* __restrict__ eBtot) {
  int n = blockIdx.x, bh = blockIdx.y;
  int b = bh >> 3, h = bh & 7;
  int t = threadIdx.x;  // kd
  int kdg = h * DKc + t;
  int trow = b * Tt + n * CHUNKc;
  __shared__ float g1s[CHUNKc * 16];
#pragma unroll
  for (int i = 0; i < 8; ++i) {
    int flat = i * 128 + t;
    int c = flat >> 4, r = flat & 15;
    g1s[flat] = g1[(size_t)(trow + c) * 128 + r];
  }
  float wc[16];
#pragma unroll
  for (int r = 0; r < 16; ++r) wc[r] = Wg2[r * KDIM + kdg];
  float bias = bg2[kdg];

  float suffix = 0.f, Ln = 0.f, Btot = 0.f;
#pragma unroll
  for (int m = 0; m < NCHUNK; ++m) {
    float Lm = L[((size_t)bh * NCHUNK + m) * DKc + t];
    if (m > n) suffix += Lm;
    if (m == n) Ln = Lm;
    Btot += Lm;
  }
  if (n == 0) eBtot[bh * DKc + t] = __expf(Btot);
  __syncthreads();

  float run = 0.f;
  size_t obase = ((size_t)bh * DKc + t) * (size_t)Tt + (size_t)n * CHUNKc;
  for (int cg = 0; cg < 8; ++cg) {
    ushort8v kw8, k8;
    if (KLAY == 1) k8 = *(const ushort8v*)(kwT + obase + cg * 8);
#pragma unroll
    for (int j = 0; j < 8; ++j) {
      int c = cg * 8 + j;
      float dot = bias;
#pragma unroll
      for (int r = 0; r < 16; ++r) dot = fmaf(g1s[c * 16 + r], wc[r], dot);
      run += logsig(dot) * (1.0f / GLNf);
      float w = __expf(suffix + Ln - run);  // exponent <= 0 always
      float kv = (KLAY == 1) ? bf2f(k8[j]) : bf2f(kb[(size_t)(trow + c) * KDIM + kdg]);
      kw8[j] = f2bf(kv * w);
    }
    *(ushort8v*)(kwT + obase + cg * 8) = kw8;
  }
}

// ------------- S_part[ks][bh] = kwT[bh](128 x Kslice) @ vT[bh](Kslice x 256)^T -------------
__global__ __launch_bounds__(256) void kv_gemm_kernel(const ushort* __restrict__ kwT,
                                                      const ushort* __restrict__ vT,
                                                      float* __restrict__ Spart) {
  __shared__ __align__(16) ushort As[128 * 32];
  __shared__ __align__(16) ushort Bs[128 * 32];
  int bn = blockIdx.x;  // vv tile 0..1
  int bh = blockIdx.y;  // 0..31
  int ks = blockIdx.z;  // split-K 0..3
  const ushort* A = kwT + (size_t)bh * DKc * Tt;
  const ushort* B = vT + (size_t)(bh * DVc + bn * 128) * Tt;
  int wave = threadIdx.x >> 6;
  int lane = threadIdx.x & 63;
  int wm = wave >> 1, wn = wave & 1;
  int lrow = lane & 15;
  int quad = lane >> 4;
  int rowInChunk = lane >> 2;
  int kElem = (lane & 3) * 8;

  f32x4 acc[4][4] = {};
  int kk0 = ks * 512;
  for (int kk = kk0; kk < kk0 + 512; kk += 32) {
#pragma unroll
    for (int r = 0; r < 2; ++r) {
      int chunk = wave * 2 + r;
      int arow = chunk * 16 + rowInChunk;
      const ushort* ga = A + (size_t)arow * Tt + kk + kElem;
      const ushort* gb = B + (size_t)arow * Tt + kk + kElem;
      __builtin_amdgcn_global_load_lds((__attribute__((address_space(1))) void*)ga,
                                       (__attribute__((address_space(3))) void*)(As + chunk * 512),
                                       16, 0, 0);
      __builtin_amdgcn_global_load_lds((__attribute__((address_space(1))) void*)gb,
                                       (__attribute__((address_space(3))) void*)(Bs + chunk * 512),
                                       16, 0, 0);
    }
    __syncthreads();
    bf16x8 af[4], bfr[4];
#pragma unroll
    for (int i = 0; i < 4; ++i) af[i] = *(const bf16x8*)(As + (wm * 64 + i * 16 + lrow) * 32 + quad * 8);
#pragma unroll
    for (int j = 0; j < 4; ++j) bfr[j] = *(const bf16x8*)(Bs + (wn * 64 + j * 16 + lrow) * 32 + quad * 8);
#pragma unroll
    for (int i = 0; i < 4; ++i)
#pragma unroll
      for (int j = 0; j < 4; ++j)
        acc[i][j] = __builtin_amdgcn_mfma_f32_16x16x32_bf16(af[i], bfr[j], acc[i][j], 0, 0, 0);
    __syncthreads();
  }

  float* Sp = Spart + ((size_t)ks * NBH + bh) * (DKc * DVc);
#pragma unroll
  for (int i = 0; i < 4; ++i) {
    int row0 = wm * 64 + i * 16 + quad * 4;  // kd
#pragma unroll
    for (int j = 0; j < 4; ++j) {
      int col = bn * 128 + wn * 64 + j * 16 + lrow;  // vv
#pragma unroll
      for (int rg = 0; rg < 4; ++rg)
        Sp[(size_t)(row0 + rg) * DVc + col] = acc[i][j][rg];
    }
  }
}

// ------------- out = S0*eBtot + sum_ks Spart -------------
__global__ __launch_bounds__(256) void reduce_kernel(const float* __restrict__ Spart,
                                                     const float* __restrict__ eBtot,
                                                     const float* __restrict__ S0,
                                                     float* __restrict__ out) {
  int i4 = blockIdx.x * 256 + threadIdx.x;
  int idx = i4 * 4;
  int bh = idx >> 15;
  int kd = (idx >> 8) & 127;
  float e = eBtot[bh * DKc + kd];
  float4 a = ((const float4*)S0)[i4];
  float4 p0 = ((const float4*)Spart)[i4];
  float4 p1 = ((const float4*)Spart)[i4 + 262144];
  float4 p2 = ((const float4*)Spart)[i4 + 524288];
  float4 p3 = ((const float4*)Spart)[i4 + 786432];
  float4 r;
  r.x = a.x * e + p0.x + p1.x + p2.x + p3.x;
  r.y = a.y * e + p0.y + p1.y + p2.y + p3.y;
  r.z = a.z * e + p0.z + p1.z + p2.z + p3.z;
  r.w = a.w * e + p0.w + p1.w + p2.w + p3.w;
  ((float4*)out)[i4] = r;
}

extern "C" void kernel_launch(void* const* d_in, const int* in_sizes, int n_in,
                              void* d_out, int out_size, void* d_ws, size_t ws_size,
                              hipStream_t stream) {
  const float* seg = (const float*)d_in[0];
  const float* norm_w = (const float*)d_in[1];
  const float* Wk = (const float*)d_in[2];
  const float* Wv = (const float*)d_in[3];
  const float* Wg1 = (const float*)d_in[4];
  const float* Wg2 = (const float*)d_in[5];
  const float* bg2 = (const float*)d_in[6];
  const float* S0 = (const float*)d_in[7];
  float* out = (float*)d_out;
  char* ws = (char*)d_ws;

  // Fused layout high-water: 80MiB + 12.5MiB (Wall) + 512KiB (Lbuf) + 16KiB (eBtot)
  const size_t FUSED_NEED = 83886080ULL + 13107200ULL + 524288ULL + 16384ULL;  // 97,533,952

  if (ws_size >= FUSED_NEED) {
    // ---- FUSED path (93.02 MiB) ----
    // regA 32MiB: xb bf16[8192][2048] -> (dead after gemm_fused) Spart f32[4][32][128][256]
    // regB 32MiB: vT bf16[32][256][2048]
    // regD 16MiB: kT bf16[32][128][2048] -> kwT in place (weight_kernel RMW)
    // regC 12.5MiB: W_allT bf16[3200][2048]
    // tail: Lbuf f32[32][32][128], eBtot f32[32][128]
    // d_out: g1 f32[8192][128] (dead before reduce_kernel rewrites d_out)
    char* regA = ws;
    char* regB = ws + (size_t)32 * 1024 * 1024;
    char* regD = ws + (size_t)64 * 1024 * 1024;
    char* regC = ws + (size_t)80 * 1024 * 1024;
    float* Lbuf = (float*)(regC + 13107200);
    float* eBtot = (float*)(regC + 13107200 + 524288);

    ushort* xb = (ushort*)regA;
    float* Spart = (float*)regA;
    ushort* vT = (ushort*)regB;
    ushort* kwT = (ushort*)regD;
    ushort* Wall = (ushort*)regC;
    float* g1buf = (float*)d_out;

    rmsnorm_kernel<<<Mrows, 256, 0, stream>>>(seg, norm_w, xb);
    transpose_all_kernel<<<dim3(64, 100), 256, 0, stream>>>(Wv, Wk, Wg1, Wall);
    gemm_fused_kernel<<<dim3(64, 25), 256, 0, stream>>>(xb, Wall, vT, kwT, g1buf);
    chunksum_kernel<<<dim3(NCHUNK, NBH), 128, 0, stream>>>(g1buf, Wg2, bg2, Lbuf);
    weight_kernel<1><<<dim3(NCHUNK, NBH), 128, 0, stream>>>(g1buf, Wg2, bg2, kwT, Lbuf, kwT, eBtot);
    kv_gemm_kernel<<<dim3(2, NBH, 4), 256, 0, stream>>>(kwT, vT, Spart);
    reduce_kernel<<<1024, 256, 0, stream>>>(Spart, eBtot, S0, out);
  } else {
    // ---- FALLBACK: exact R5 layout (84.02 MiB, proven) ----
    char* regA = ws;
    char* regB = ws + (size_t)32 * 1024 * 1024;
    char* regD = ws + (size_t)64 * 1024 * 1024;
    char* regC = ws + (size_t)80 * 1024 * 1024;
    float* eBtot = (float*)(ws + (size_t)84 * 1024 * 1024);

    ushort* xb = (ushort*)regA;
    ushort* kwT = (ushort*)regA;
    float* Spart = (float*)(regA + 16777216);
    ushort* vT = (ushort*)regB;
    ushort* kb = (ushort*)regD;
    ushort* WvTh = (ushort*)regC;
    ushort* WkT = (ushort*)regC;
    float* g1buf = (float*)regC;
    ushort* WgT = (ushort*)d_out;
    float* Lbuf = (float*)((char*)d_out + 2097152);

    rmsnorm_kernel<<<Mrows, 256, 0, stream>>>(seg, norm_w, xb);

    transpose_cast_kernel<<<dim3(64, 32), 256, 0, stream>>>(Wv, WvTh, VDIM, VDIM, 0);
    gemm_kernel<2><<<dim3(64, 8), 256, 0, stream>>>(xb, WvTh, vT, VDIM, Dd, 0);
    transpose_cast_kernel<<<dim3(64, 32), 256, 0, stream>>>(Wv, WvTh, VDIM, VDIM, 1024);
    gemm_kernel<2><<<dim3(64, 8), 256, 0, stream>>>(xb, WvTh, vT, VDIM, Dd, 8);

    transpose_cast_kernel<<<dim3(64, 32), 256, 0, stream>>>(Wk, WkT, KDIM, KDIM, 0);
    gemm_kernel<1><<<dim3(64, 8), 256, 0, stream>>>(xb, WkT, kb, KDIM, Dd, 0);

    transpose_cast_kernel<<<dim3(64, 4), 256, 0, stream>>>(Wg1, WgT, 16, 16, 0);
    gemm_kernel<0><<<dim3(64, 1), 256, 0, stream>>>(xb, WgT, g1buf, 128, Dd, 0);

    chunksum_kernel<<<dim3(NCHUNK, NBH), 128, 0, stream>>>(g1buf, Wg2, bg2, Lbuf);
    weight_kernel<0><<<dim3(NCHUNK, NBH), 128, 0, stream>>>(g1buf, Wg2, bg2, kb, Lbuf, kwT, eBtot);
    kv_gemm_kernel<<<dim3(2, NBH, 4), 256, 0, stream>>>(kwT, vT, Spart);
    reduce_kernel<<<1024, 256, 0, stream>>>(Spart, eBtot, S0, out);
  }
}

// Round 7
// 360.048 us; speedup vs baseline: 1.9500x; 1.0448x over previous
//
#include <hip/hip_runtime.h>
#include <math.h>

#define Hh 8
#define DKc 128
#define DVc 256
#define CHUNKc 64
#define GLNf 16.0f
#define EPSf 1e-5f

#define Bb 4
#define Tt 2048
#define Dd 2048
#define KDIM 1024
#define VDIM 2048
#define Mrows 8192
#define NCHUNK 32
#define NBH 32

typedef short bf16x8 __attribute__((ext_vector_type(8)));
typedef float f32x4 __attribute__((ext_vector_type(4)));
typedef ushort ushort8v __attribute__((ext_vector_type(8)));

__device__ inline ushort f2bf(float f) {
  unsigned u = __float_as_uint(f);
  unsigned r = (u + 0x7fffu + ((u >> 16) & 1u)) >> 16;
  return (ushort)r;
}
__device__ inline float bf2f(ushort u) {
  return __uint_as_float(((unsigned)u) << 16);
}
// log_sigmoid(g) = min(g,0) - log(1 + exp(-|g|)); branch-free, hw v_exp/v_log.
__device__ inline float logsig(float g) {
  return fminf(g, 0.f) - __logf(1.f + __expf(-fabsf(g)));
}

// ---------------- RMSNorm + bf16 cast: one block per row ----------------
__global__ __launch_bounds__(256) void rmsnorm_kernel(const float* __restrict__ seg,
                                                      const float* __restrict__ norm_w,
                                                      ushort* __restrict__ xb) {
  int row = blockIdx.x;
  int t = threadIdx.x;
  const float4* p = (const float4*)(seg + (size_t)row * Dd);
  float4 a = p[t];
  float4 b = p[t + 256];
  float ss = a.x * a.x + a.y * a.y + a.z * a.z + a.w * a.w +
             b.x * b.x + b.y * b.y + b.z * b.z + b.w * b.w;
#pragma unroll
  for (int off = 32; off > 0; off >>= 1) ss += __shfl_down(ss, off);
  __shared__ float red[4];
  if ((t & 63) == 0) red[t >> 6] = ss;
  __syncthreads();
  float tot = red[0] + red[1] + red[2] + red[3];
  float scale = rsqrtf(tot * (1.0f / (float)Dd) + EPSf);
  const float4* w4 = (const float4*)norm_w;
  float4 wa = w4[t], wb = w4[t + 256];
  ushort4 oa, ob;
  oa.x = f2bf(a.x * scale * wa.x);
  oa.y = f2bf(a.y * scale * wa.y);
  oa.z = f2bf(a.z * scale * wa.z);
  oa.w = f2bf(a.w * scale * wa.w);
  ob.x = f2bf(b.x * scale * wb.x);
  ob.y = f2bf(b.y * scale * wb.y);
  ob.z = f2bf(b.z * scale * wb.z);
  ob.w = f2bf(b.w * scale * wb.w);
  ushort4* o4 = (ushort4*)(xb + (size_t)row * Dd);
  o4[t] = oa;
  o4[t + 256] = ob;
}

// --- fused transpose: W_allT[3200][2048] = [Wv^T(2048) ; Wk^T(1024) ; Wg1^T pad(128)] ---
__global__ __launch_bounds__(256) void transpose_all_kernel(const float* __restrict__ Wv,
                                                            const float* __restrict__ Wk,
                                                            const float* __restrict__ Wg1,
                                                            ushort* __restrict__ Wall) {
  const int K = 2048;
  __shared__ float tile[32][33];
  int k0 = blockIdx.x * 32;
  int n0 = blockIdx.y * 32;  // output row base 0..3168
  const float* src;
  int N, stride, nb;
  if (n0 < 2048) {
    src = Wv; N = 2048; stride = 2048; nb = n0;
  } else if (n0 < 3072) {
    src = Wk; N = 1024; stride = 1024; nb = n0 - 2048;
  } else {
    src = Wg1; N = 16; stride = 16; nb = n0 - 3072;
  }
  int tx = threadIdx.x & 31;
  int ty = threadIdx.x >> 5;
#pragma unroll
  for (int i = 0; i < 32; i += 8) {
    int k = k0 + ty + i;
    int n = nb + tx;
    tile[ty + i][tx] = (n < N) ? src[(size_t)k * stride + n] : 0.0f;
  }
  __syncthreads();
#pragma unroll
  for (int i = 0; i < 32; i += 8) {
    Wall[(size_t)(n0 + ty + i) * K + k0 + tx] = f2bf(tile[tx][ty + i]);
  }
}

// --- per-batch bf16 transpose: xT[b][d][t] from xb[(b*2048+t)][d] ---
__global__ __launch_bounds__(256) void transpose_x_kernel(const ushort* __restrict__ xb,
                                                          ushort* __restrict__ xT) {
  __shared__ ushort tile[32][34];  // +2 pad: bank = tx*17 mod 32, conflict-free
  int b = blockIdx.z;
  int t0 = blockIdx.x * 32;
  int d0 = blockIdx.y * 32;
  int tx = threadIdx.x & 31;
  int ty = threadIdx.x >> 5;  // 0..7
#pragma unroll
  for (int i = 0; i < 32; i += 8)
    tile[ty + i][tx] = xb[((size_t)b * Tt + t0 + ty + i) * Dd + d0 + tx];
  __syncthreads();
#pragma unroll
  for (int i = 0; i < 32; i += 8)
    xT[((size_t)b * Dd + d0 + ty + i) * Tt + t0 + tx] = tile[tx][ty + i];
}

// ------- GEMM1: xb[8192][2048] @ Wallk[1152][2048]^T; bn<8 -> kT[bh][kd][t], bn==8 -> g1 -------
__global__ __launch_bounds__(256) void gemm_kg_kernel(const ushort* __restrict__ A,
                                                      const ushort* __restrict__ Wallk,
                                                      ushort* __restrict__ kT,
                                                      float* __restrict__ g1) {
  __shared__ __align__(16) ushort As[128 * 32];
  __shared__ __align__(16) ushort Bs[128 * 32];
  int bm = blockIdx.x;
  int bn = blockIdx.y;  // 0..8
  int wave = threadIdx.x >> 6;
  int lane = threadIdx.x & 63;
  int wm = wave >> 1, wn = wave & 1;
  int lrow = lane & 15;
  int quad = lane >> 4;
  int rowInChunk = lane >> 2;
  int kElem = (lane & 3) * 8;

  f32x4 acc[4][4] = {};
  for (int kk = 0; kk < Dd; kk += 32) {
#pragma unroll
    for (int r = 0; r < 2; ++r) {
      int chunk = wave * 2 + r;
      int arow = chunk * 16 + rowInChunk;
      const ushort* ga = A + ((size_t)(bm * 128 + arow)) * Dd + kk + kElem;
      const ushort* gb = Wallk + ((size_t)(bn * 128 + arow)) * Dd + kk + kElem;
      __builtin_amdgcn_global_load_lds((__attribute__((address_space(1))) void*)ga,
                                       (__attribute__((address_space(3))) void*)(As + chunk * 512),
                                       16, 0, 0);
      __builtin_amdgcn_global_load_lds((__attribute__((address_space(1))) void*)gb,
                                       (__attribute__((address_space(3))) void*)(Bs + chunk * 512),
                                       16, 0, 0);
    }
    __syncthreads();
    bf16x8 af[4], bfr[4];
#pragma unroll
    for (int i = 0; i < 4; ++i) af[i] = *(const bf16x8*)(As + (wm * 64 + i * 16 + lrow) * 32 + quad * 8);
#pragma unroll
    for (int j = 0; j < 4; ++j) bfr[j] = *(const bf16x8*)(Bs + (wn * 64 + j * 16 + lrow) * 32 + quad * 8);
#pragma unroll
    for (int i = 0; i < 4; ++i)
#pragma unroll
      for (int j = 0; j < 4; ++j)
        acc[i][j] = __builtin_amdgcn_mfma_f32_16x16x32_bf16(af[i], bfr[j], acc[i][j], 0, 0, 0);
    __syncthreads();
  }

#pragma unroll
  for (int i = 0; i < 4; ++i) {
    int m0 = bm * 128 + wm * 64 + i * 16 + quad * 4;
    int b = m0 >> 11, tloc = m0 & 2047;
#pragma unroll
    for (int j = 0; j < 4; ++j) {
      int col = bn * 128 + wn * 64 + j * 16 + lrow;
      if (bn < 8) {  // k: kT[bh][kd][t]
        int h = col >> 7, kd = col & 127;
        ushort4 o;
        o.x = f2bf(acc[i][j][0]);
        o.y = f2bf(acc[i][j][1]);
        o.z = f2bf(acc[i][j][2]);
        o.w = f2bf(acc[i][j][3]);
        *(ushort4*)(kT + ((size_t)((b * 8 + h) * 128 + kd)) * 2048 + tloc) = o;
      } else {  // g1 fp32 [8192][128]
        int cg = col - 1024;
#pragma unroll
        for (int rg = 0; rg < 4; ++rg)
          g1[(size_t)(m0 + rg) * 128 + cg] = acc[i][j][rg];
      }
    }
  }
}

// ------- GEMM2: Y[bh][kd][d] = kwT[bh](128 x 2048_t) @ xT[b](2048_d x 2048_t)^T -------
__global__ __launch_bounds__(256) void gemm_y_kernel(const ushort* __restrict__ kwT,
                                                     const ushort* __restrict__ xT,
                                                     ushort* __restrict__ Y) {
  __shared__ __align__(16) ushort As[128 * 32];
  __shared__ __align__(16) ushort Bs[128 * 32];
  int bn = blockIdx.x;  // d tile 0..15
  int bh = blockIdx.y;  // 0..31
  int b = bh >> 3;
  const ushort* A = kwT + (size_t)bh * DKc * Tt;
  const ushort* B = xT + (size_t)b * Dd * Tt;
  int wave = threadIdx.x >> 6;
  int lane = threadIdx.x & 63;
  int wm = wave >> 1, wn = wave & 1;
  int lrow = lane & 15;
  int quad = lane >> 4;
  int rowInChunk = lane >> 2;
  int kElem = (lane & 3) * 8;

  f32x4 acc[4][4] = {};
  for (int kk = 0; kk < Tt; kk += 32) {
#pragma unroll
    for (int r = 0; r < 2; ++r) {
      int chunk = wave * 2 + r;
      int arow = chunk * 16 + rowInChunk;
      const ushort* ga = A + (size_t)arow * Tt + kk + kElem;
      const ushort* gb = B + ((size_t)(bn * 128 + arow)) * Tt + kk + kElem;
      __builtin_amdgcn_global_load_lds((__attribute__((address_space(1))) void*)ga,
                                       (__attribute__((address_space(3))) void*)(As + chunk * 512),
                                       16, 0, 0);
      __builtin_amdgcn_global_load_lds((__attribute__((address_space(1))) void*)gb,
                                       (__attribute__((address_space(3))) void*)(Bs + chunk * 512),
                                       16, 0, 0);
    }
    __syncthreads();
    bf16x8 af[4], bfr[4];
#pragma unroll
    for (int i = 0; i < 4; ++i) af[i] = *(const bf16x8*)(As + (wm * 64 + i * 16 + lrow) * 32 + quad * 8);
#pragma unroll
    for (int j = 0; j < 4; ++j) bfr[j] = *(const bf16x8*)(Bs + (wn * 64 + j * 16 + lrow) * 32 + quad * 8);
#pragma unroll
    for (int i = 0; i < 4; ++i)
#pragma unroll
      for (int j = 0; j < 4; ++j)
        acc[i][j] = __builtin_amdgcn_mfma_f32_16x16x32_bf16(af[i], bfr[j], acc[i][j], 0, 0, 0);
    __syncthreads();
  }

#pragma unroll
  for (int i = 0; i < 4; ++i) {
    int row0 = wm * 64 + i * 16 + quad * 4;  // kd
#pragma unroll
    for (int j = 0; j < 4; ++j) {
      int col = bn * 128 + wn * 64 + j * 16 + lrow;  // d
#pragma unroll
      for (int rg = 0; rg < 4; ++rg)
        Y[((size_t)bh * DKc + row0 + rg) * Dd + col] = f2bf(acc[i][j][rg]);
    }
  }
}

// ------- GEMM3: out[bh] = Y[bh](128 x 2048_d) @ WvT_h(256 x 2048_d)^T + S0*eBtot -------
__global__ __launch_bounds__(256) void gemm_out_kernel(const ushort* __restrict__ Y,
                                                       const ushort* __restrict__ WvT,
                                                       const float* __restrict__ eBtot,
                                                       const float* __restrict__ S0,
                                                       float* __restrict__ out) {
  __shared__ __align__(16) ushort As[128 * 32];
  __shared__ __align__(16) ushort Bs[128 * 32];
  int bn = blockIdx.x;  // vv tile 0..1
  int bh = blockIdx.y;  // 0..31
  int h = bh & 7;
  const ushort* A = Y + (size_t)bh * DKc * Dd;
  const ushort* B = WvT + (size_t)(h * DVc + bn * 128) * Dd;
  int wave = threadIdx.x >> 6;
  int lane = threadIdx.x & 63;
  int wm = wave >> 1, wn = wave & 1;
  int lrow = lane & 15;
  int quad = lane >> 4;
  int rowInChunk = lane >> 2;
  int kElem = (lane & 3) * 8;

  f32x4 acc[4][4] = {};
  for (int kk = 0; kk < Dd; kk += 32) {
#pragma unroll
    for (int r = 0; r < 2; ++r) {
      int chunk = wave * 2 + r;
      int arow = chunk * 16 + rowInChunk;
      const ushort* ga = A + (size_t)arow * Dd + kk + kElem;
      const ushort* gb = B + (size_t)arow * Dd + kk + kElem;
      __builtin_amdgcn_global_load_lds((__attribute__((address_space(1))) void*)ga,
                                       (__attribute__((address_space(3))) void*)(As + chunk * 512),
                                       16, 0, 0);
      __builtin_amdgcn_global_load_lds((__attribute__((address_space(1))) void*)gb,
                                       (__attribute__((address_space(3))) void*)(Bs + chunk * 512),
                                       16, 0, 0);
    }
    __syncthreads();
    bf16x8 af[4], bfr[4];
#pragma unroll
    for (int i = 0; i < 4; ++i) af[i] = *(const bf16x8*)(As + (wm * 64 + i * 16 + lrow) * 32 + quad * 8);
#pragma unroll
    for (int j = 0; j < 4; ++j) bfr[j] = *(const bf16x8*)(Bs + (wn * 64 + j * 16 + lrow) * 32 + quad * 8);
#pragma unroll
    for (int i = 0; i < 4; ++i)
#pragma unroll
      for (int j = 0; j < 4; ++j)
        acc[i][j] = __builtin_amdgcn_mfma_f32_16x16x32_bf16(af[i], bfr[j], acc[i][j], 0, 0, 0);
    __syncthreads();
  }

  size_t base = (size_t)bh * DKc * DVc;
#pragma unroll
  for (int i = 0; i < 4; ++i) {
    int row0 = wm * 64 + i * 16 + quad * 4;  // kd
#pragma unroll
    for (int j = 0; j < 4; ++j) {
      int col = bn * 128 + wn * 64 + j * 16 + lrow;  // vv
#pragma unroll
      for (int rg = 0; rg < 4; ++rg) {
        int r = row0 + rg;
        out[base + (size_t)r * DVc + col] =
            S0[base + (size_t)r * DVc + col] * eBtot[bh * DKc + r] + acc[i][j][rg];
      }
    }
  }
}

// ------------- chunk gate sums: L[bh][n][kd] = sum_c logsig(g1@Wg2col + b)/GLN -------------
__global__ __launch_bounds__(128) void chunksum_kernel(const float* __restrict__ g1,
                                                       const float* __restrict__ Wg2,
                                                       const float* __restrict__ bg2,
                                                       float* __restrict__ L) {
  int n = blockIdx.x, bh = blockIdx.y;
  int b = bh >> 3, h = bh & 7;
  int t = threadIdx.x;  // kd
  int kdg = h * DKc + t;
  int trow = b * Tt + n * CHUNKc;
  __shared__ float g1s[CHUNKc * 16];
#pragma unroll
  for (int i = 0; i < 8; ++i) {
    int flat = i * 128 + t;
    int c = flat >> 4, r = flat & 15;
    g1s[flat] = g1[(size_t)(trow + c) * 128 + r];
  }
  float wc[16];
#pragma unroll
  for (int r = 0; r < 16; ++r) wc[r] = Wg2[r * KDIM + kdg];
  float bias = bg2[kdg];
  __syncthreads();
  float sum = 0.f;
  for (int c = 0; c < CHUNKc; ++c) {
    float dot = bias;
#pragma unroll
    for (int r = 0; r < 16; ++r) dot = fmaf(g1s[c * 16 + r], wc[r], dot);
    sum += logsig(dot) * (1.0f / GLNf);
  }
  L[((size_t)bh * NCHUNK + n) * DKc + t] = sum;
}

// ------------- weights: kwT[bh][kd][t] = bf16(k * exp(Btot - B_t)) in place; eBtot -------------
__global__ __launch_bounds__(128) void weight_kernel(const float* __restrict__ g1,
                                                     const float* __restrict__ Wg2,
                                                     const float* __restrict__ bg2,
                                                     const float* __restrict__ L,
                                                     ushort* __restrict__ kwT,
                                                     float* __restrict__ eBtot) {
  int n = blockIdx.x, bh = blockIdx.y;
  int b = bh >> 3, h = bh & 7;
  int t = threadIdx.x;  // kd
  int kdg = h * DKc + t;
  int trow = b * Tt + n * CHUNKc;
  __shared__ float g1s[CHUNKc * 16];
#pragma unroll
  for (int i = 0; i < 8; ++i) {
    int flat = i * 128 + t;
    int c = flat >> 4, r = flat & 15;
    g1s[flat] = g1[(size_t)(trow + c) * 128 + r];
  }
  float wc[16];
#pragma unroll
  for (int r = 0; r < 16; ++r) wc[r] = Wg2[r * KDIM + kdg];
  float bias = bg2[kdg];

  float suffix = 0.f, Ln = 0.f, Btot = 0.f;
#pragma unroll
  for (int m = 0; m < NCHUNK; ++m) {
    float Lm = L[((size_t)bh * NCHUNK + m) * DKc + t];
    if (m > n) suffix += Lm;
    if (m == n) Ln = Lm;
    Btot += Lm;
  }
  if (n == 0) eBtot[bh * DKc + t] = __expf(Btot);
  __syncthreads();

  float run = 0.f;
  size_t obase = ((size_t)bh * DKc + t) * (size_t)Tt + (size_t)n * CHUNKc;
  for (int cg = 0; cg < 8; ++cg) {
    ushort8v kw8;
    ushort8v k8 = *(const ushort8v*)(kwT + obase + cg * 8);
#pragma unroll
    for (int j = 0; j < 8; ++j) {
      int c = cg * 8 + j;
      float dot = bias;
#pragma unroll
      for (int r = 0; r < 16; ++r) dot = fmaf(g1s[c * 16 + r], wc[r], dot);
      run += logsig(dot) * (1.0f / GLNf);
      float w = __expf(suffix + Ln - run);  // exponent <= 0 always
      kw8[j] = f2bf(bf2f(k8[j]) * w);
    }
    *(ushort8v*)(kwT + obase + cg * 8) = kw8;
  }
}

extern "C" void kernel_launch(void* const* d_in, const int* in_sizes, int n_in,
                              void* d_out, int out_size, void* d_ws, size_t ws_size,
                              hipStream_t stream) {
  const float* seg = (const float*)d_in[0];
  const float* norm_w = (const float*)d_in[1];
  const float* Wk = (const float*)d_in[2];
  const float* Wv = (const float*)d_in[3];
  const float* Wg1 = (const float*)d_in[4];
  const float* Wg2 = (const float*)d_in[5];
  const float* bg2 = (const float*)d_in[6];
  const float* S0 = (const float*)d_in[7];
  float* out = (float*)d_out;
  char* ws = (char*)d_ws;

  // ---- workspace 93.65 MiB (< 97.53 MiB proven available in R6) ----
  // regA 32MiB: xb bf16[8192][2048] -> (dead after gemm_kg + transpose_x) Y bf16[32][128][2048]
  // regB 32MiB: xT bf16[4][2048][2048]
  // regD 16MiB: kT bf16[32][128][2048] -> kwT in place (weight_kernel RMW)
  // regC 12.5MiB: W_allT bf16[3200][2048] = [Wv^T ; Wk^T ; Wg1^T pad]; then Lbuf, eBtot
  // d_out: g1 f32[8192][128] (dead before gemm_out writes d_out)
  char* regA = ws;
  char* regB = ws + (size_t)32 * 1024 * 1024;
  char* regD = ws + (size_t)64 * 1024 * 1024;
  char* regC = ws + (size_t)80 * 1024 * 1024;
  float* Lbuf = (float*)(regC + 13107200);
  float* eBtot = (float*)(regC + 13107200 + 524288);

  ushort* xb = (ushort*)regA;
  ushort* Y = (ushort*)regA;     // after xb dead
  ushort* xT = (ushort*)regB;
  ushort* kwT = (ushort*)regD;
  ushort* Wall = (ushort*)regC;
  ushort* Wallk = Wall + (size_t)2048 * 2048;  // rows 2048.. = [Wk^T ; Wg1^T]
  float* g1buf = (float*)d_out;

  rmsnorm_kernel<<<Mrows, 256, 0, stream>>>(seg, norm_w, xb);
  transpose_all_kernel<<<dim3(64, 100), 256, 0, stream>>>(Wv, Wk, Wg1, Wall);
  transpose_x_kernel<<<dim3(64, 64, 4), 256, 0, stream>>>(xb, xT);
  gemm_kg_kernel<<<dim3(64, 9), 256, 0, stream>>>(xb, Wallk, kwT, g1buf);
  chunksum_kernel<<<dim3(NCHUNK, NBH), 128, 0, stream>>>(g1buf, Wg2, bg2, Lbuf);
  weight_kernel<<<dim3(NCHUNK, NBH), 128, 0, stream>>>(g1buf, Wg2, bg2, Lbuf, kwT, eBtot);
  gemm_y_kernel<<<dim3(16, NBH), 256, 0, stream>>>(kwT, xT, Y);
  gemm_out_kernel<<<dim3(2, NBH), 256, 0, stream>>>(Y, Wall, eBtot, S0, out);
}

// Round 8
// 348.116 us; speedup vs baseline: 2.0168x; 1.0343x over previous
//
#include <hip/hip_runtime.h>
#include <math.h>

#define Hh 8
#define DKc 128
#define DVc 256
#define CHUNKc 64
#define GLNf 16.0f
#define EPSf 1e-5f

#define Bb 4
#define Tt 2048
#define Dd 2048
#define KDIM 1024
#define VDIM 2048
#define Mrows 8192
#define NCHUNK 32
#define NBH 32

typedef short bf16x8 __attribute__((ext_vector_type(8)));
typedef float f32x4 __attribute__((ext_vector_type(4)));
typedef ushort ushort8v __attribute__((ext_vector_type(8)));

__device__ inline ushort f2bf(float f) {
  unsigned u = __float_as_uint(f);
  unsigned r = (u + 0x7fffu + ((u >> 16) & 1u)) >> 16;
  return (ushort)r;
}
__device__ inline float bf2f(ushort u) {
  return __uint_as_float(((unsigned)u) << 16);
}
// log_sigmoid(g) = min(g,0) - log(1 + exp(-|g|)); branch-free, hw v_exp/v_log.
__device__ inline float logsig(float g) {
  return fminf(g, 0.f) - __logf(1.f + __expf(-fabsf(g)));
}

// ---------------- RMSNorm + bf16 cast: one block per row ----------------
__global__ __launch_bounds__(256) void rmsnorm_kernel(const float* __restrict__ seg,
                                                      const float* __restrict__ norm_w,
                                                      ushort* __restrict__ xb) {
  int row = blockIdx.x;
  int t = threadIdx.x;
  const float4* p = (const float4*)(seg + (size_t)row * Dd);
  float4 a = p[t];
  float4 b = p[t + 256];
  float ss = a.x * a.x + a.y * a.y + a.z * a.z + a.w * a.w +
             b.x * b.x + b.y * b.y + b.z * b.z + b.w * b.w;
#pragma unroll
  for (int off = 32; off > 0; off >>= 1) ss += __shfl_down(ss, off);
  __shared__ float red[4];
  if ((t & 63) == 0) red[t >> 6] = ss;
  __syncthreads();
  float tot = red[0] + red[1] + red[2] + red[3];
  float scale = rsqrtf(tot * (1.0f / (float)Dd) + EPSf);
  const float4* w4 = (const float4*)norm_w;
  float4 wa = w4[t], wb = w4[t + 256];
  ushort4 oa, ob;
  oa.x = f2bf(a.x * scale * wa.x);
  oa.y = f2bf(a.y * scale * wa.y);
  oa.z = f2bf(a.z * scale * wa.z);
  oa.w = f2bf(a.w * scale * wa.w);
  ob.x = f2bf(b.x * scale * wb.x);
  ob.y = f2bf(b.y * scale * wb.y);
  ob.z = f2bf(b.z * scale * wb.z);
  ob.w = f2bf(b.w * scale * wb.w);
  ushort4* o4 = (ushort4*)(xb + (size_t)row * Dd);
  o4[t] = oa;
  o4[t + 256] = ob;
}

// --- fused transpose: W_allT[3200][2048] = [Wv^T(2048) ; Wk^T(1024) ; Wg1^T pad(128)] ---
__global__ __launch_bounds__(256) void transpose_all_kernel(const float* __restrict__ Wv,
                                                            const float* __restrict__ Wk,
                                                            const float* __restrict__ Wg1,
                                                            ushort* __restrict__ Wall) {
  const int K = 2048;
  __shared__ float tile[32][33];
  int k0 = blockIdx.x * 32;
  int n0 = blockIdx.y * 32;
  const float* src;
  int N, stride, nb;
  if (n0 < 2048) {
    src = Wv; N = 2048; stride = 2048; nb = n0;
  } else if (n0 < 3072) {
    src = Wk; N = 1024; stride = 1024; nb = n0 - 2048;
  } else {
    src = Wg1; N = 16; stride = 16; nb = n0 - 3072;
  }
  int tx = threadIdx.x & 31;
  int ty = threadIdx.x >> 5;
#pragma unroll
  for (int i = 0; i < 32; i += 8) {
    int k = k0 + ty + i;
    int n = nb + tx;
    tile[ty + i][tx] = (n < N) ? src[(size_t)k * stride + n] : 0.0f;
  }
  __syncthreads();
#pragma unroll
  for (int i = 0; i < 32; i += 8) {
    Wall[(size_t)(n0 + ty + i) * K + k0 + tx] = f2bf(tile[tx][ty + i]);
  }
}

// --- per-batch bf16 transpose v2: 64x64 tiles, ushort4 global, stride-65 LDS ---
__global__ __launch_bounds__(256) void transpose_x_kernel(const ushort* __restrict__ xb,
                                                          ushort* __restrict__ xT) {
  __shared__ ushort tile[64 * 65];
  int b = blockIdx.z;
  int t0 = blockIdx.x * 64;
  int d0 = blockIdx.y * 64;
  int tx = threadIdx.x & 15;   // d quad
  int ty = threadIdx.x >> 4;   // 0..15
#pragma unroll
  for (int i = 0; i < 4; ++i) {
    int t = i * 16 + ty;
    ushort4 v = *(const ushort4*)(xb + ((size_t)b * Tt + t0 + t) * Dd + d0 + tx * 4);
    tile[t * 65 + tx * 4 + 0] = v.x;
    tile[t * 65 + tx * 4 + 1] = v.y;
    tile[t * 65 + tx * 4 + 2] = v.z;
    tile[t * 65 + tx * 4 + 3] = v.w;
  }
  __syncthreads();
  int tw = threadIdx.x & 15;   // t quad
  int dw = threadIdx.x >> 4;   // 0..15
#pragma unroll
  for (int j = 0; j < 4; ++j) {
    int d = j * 16 + dw;
    ushort4 o;
    o.x = tile[(tw * 4 + 0) * 65 + d];
    o.y = tile[(tw * 4 + 1) * 65 + d];
    o.z = tile[(tw * 4 + 2) * 65 + d];
    o.w = tile[(tw * 4 + 3) * 65 + d];
    *(ushort4*)(xT + ((size_t)b * Dd + d0 + d) * Tt + t0 + tw * 4) = o;
  }
}

// ------- GEMM1: xb[8192][2048] @ Wallk[1152][2048]^T; bn<8 -> kT[bh][kd][t], bn==8 -> g1 -------
// 1D grid 576: bm=idx/9, bn=idx%9 — interleaves the g1 tile (no 64-block tail),
// consecutive blocks share the A tile (L2 reuse).
__global__ __launch_bounds__(256) void gemm_kg_kernel(const ushort* __restrict__ A,
                                                      const ushort* __restrict__ Wallk,
                                                      ushort* __restrict__ kT,
                                                      float* __restrict__ g1) {
  __shared__ __align__(16) ushort As[128 * 32];
  __shared__ __align__(16) ushort Bs[128 * 32];
  int bm = blockIdx.x / 9;
  int bn = blockIdx.x % 9;
  int wave = threadIdx.x >> 6;
  int lane = threadIdx.x & 63;
  int wm = wave >> 1, wn = wave & 1;
  int lrow = lane & 15;
  int quad = lane >> 4;
  int rowInChunk = lane >> 2;
  int kElem = (lane & 3) * 8;

  f32x4 acc[4][4] = {};
  for (int kk = 0; kk < Dd; kk += 32) {
#pragma unroll
    for (int r = 0; r < 2; ++r) {
      int chunk = wave * 2 + r;
      int arow = chunk * 16 + rowInChunk;
      const ushort* ga = A + ((size_t)(bm * 128 + arow)) * Dd + kk + kElem;
      const ushort* gb = Wallk + ((size_t)(bn * 128 + arow)) * Dd + kk + kElem;
      __builtin_amdgcn_global_load_lds((__attribute__((address_space(1))) void*)ga,
                                       (__attribute__((address_space(3))) void*)(As + chunk * 512),
                                       16, 0, 0);
      __builtin_amdgcn_global_load_lds((__attribute__((address_space(1))) void*)gb,
                                       (__attribute__((address_space(3))) void*)(Bs + chunk * 512),
                                       16, 0, 0);
    }
    __syncthreads();
    bf16x8 af[4], bfr[4];
#pragma unroll
    for (int i = 0; i < 4; ++i) af[i] = *(const bf16x8*)(As + (wm * 64 + i * 16 + lrow) * 32 + quad * 8);
#pragma unroll
    for (int j = 0; j < 4; ++j) bfr[j] = *(const bf16x8*)(Bs + (wn * 64 + j * 16 + lrow) * 32 + quad * 8);
#pragma unroll
    for (int i = 0; i < 4; ++i)
#pragma unroll
      for (int j = 0; j < 4; ++j)
        acc[i][j] = __builtin_amdgcn_mfma_f32_16x16x32_bf16(af[i], bfr[j], acc[i][j], 0, 0, 0);
    __syncthreads();
  }

#pragma unroll
  for (int i = 0; i < 4; ++i) {
    int m0 = bm * 128 + wm * 64 + i * 16 + quad * 4;
    int b = m0 >> 11, tloc = m0 & 2047;
#pragma unroll
    for (int j = 0; j < 4; ++j) {
      int col = bn * 128 + wn * 64 + j * 16 + lrow;
      if (bn < 8) {  // k: kT[bh][kd][t]
        int h = col >> 7, kd = col & 127;
        ushort4 o;
        o.x = f2bf(acc[i][j][0]);
        o.y = f2bf(acc[i][j][1]);
        o.z = f2bf(acc[i][j][2]);
        o.w = f2bf(acc[i][j][3]);
        *(ushort4*)(kT + ((size_t)((b * 8 + h) * 128 + kd)) * 2048 + tloc) = o;
      } else {  // g1 fp32 [8192][128]
        int cg = col - 1024;
#pragma unroll
        for (int rg = 0; rg < 4; ++rg)
          g1[(size_t)(m0 + rg) * 128 + cg] = acc[i][j][rg];
      }
    }
  }
}

// ------- GEMM2: Y[bh][kd][d] = kwT[bh](128 x 2048_t) @ xT[b](2048_d x 2048_t)^T -------
__global__ __launch_bounds__(256) void gemm_y_kernel(const ushort* __restrict__ kwT,
                                                     const ushort* __restrict__ xT,
                                                     ushort* __restrict__ Y) {
  __shared__ __align__(16) ushort As[128 * 32];
  __shared__ __align__(16) ushort Bs[128 * 32];
  int bn = blockIdx.x;  // d tile 0..15
  int bh = blockIdx.y;  // 0..31
  int b = bh >> 3;
  const ushort* A = kwT + (size_t)bh * DKc * Tt;
  const ushort* B = xT + (size_t)b * Dd * Tt;
  int wave = threadIdx.x >> 6;
  int lane = threadIdx.x & 63;
  int wm = wave >> 1, wn = wave & 1;
  int lrow = lane & 15;
  int quad = lane >> 4;
  int rowInChunk = lane >> 2;
  int kElem = (lane & 3) * 8;

  f32x4 acc[4][4] = {};
  for (int kk = 0; kk < Tt; kk += 32) {
#pragma unroll
    for (int r = 0; r < 2; ++r) {
      int chunk = wave * 2 + r;
      int arow = chunk * 16 + rowInChunk;
      const ushort* ga = A + (size_t)arow * Tt + kk + kElem;
      const ushort* gb = B + ((size_t)(bn * 128 + arow)) * Tt + kk + kElem;
      __builtin_amdgcn_global_load_lds((__attribute__((address_space(1))) void*)ga,
                                       (__attribute__((address_space(3))) void*)(As + chunk * 512),
                                       16, 0, 0);
      __builtin_amdgcn_global_load_lds((__attribute__((address_space(1))) void*)gb,
                                       (__attribute__((address_space(3))) void*)(Bs + chunk * 512),
                                       16, 0, 0);
    }
    __syncthreads();
    bf16x8 af[4], bfr[4];
#pragma unroll
    for (int i = 0; i < 4; ++i) af[i] = *(const bf16x8*)(As + (wm * 64 + i * 16 + lrow) * 32 + quad * 8);
#pragma unroll
    for (int j = 0; j < 4; ++j) bfr[j] = *(const bf16x8*)(Bs + (wn * 64 + j * 16 + lrow) * 32 + quad * 8);
#pragma unroll
    for (int i = 0; i < 4; ++i)
#pragma unroll
      for (int j = 0; j < 4; ++j)
        acc[i][j] = __builtin_amdgcn_mfma_f32_16x16x32_bf16(af[i], bfr[j], acc[i][j], 0, 0, 0);
    __syncthreads();
  }

#pragma unroll
  for (int i = 0; i < 4; ++i) {
    int row0 = wm * 64 + i * 16 + quad * 4;  // kd
#pragma unroll
    for (int j = 0; j < 4; ++j) {
      int col = bn * 128 + wn * 64 + j * 16 + lrow;  // d
#pragma unroll
      for (int rg = 0; rg < 4; ++rg)
        Y[((size_t)bh * DKc + row0 + rg) * Dd + col] = f2bf(acc[i][j][rg]);
    }
  }
}

// ------- GEMM3 split-K: Spart[ks][bh] = Y[bh](128 x 512_d) @ WvT_h(256 x 512_d)^T -------
__global__ __launch_bounds__(256) void gemm_out_sk_kernel(const ushort* __restrict__ Y,
                                                          const ushort* __restrict__ WvT,
                                                          float* __restrict__ Spart) {
  __shared__ __align__(16) ushort As[128 * 32];
  __shared__ __align__(16) ushort Bs[128 * 32];
  int bn = blockIdx.x;  // vv tile 0..1
  int bh = blockIdx.y;  // 0..31
  int ks = blockIdx.z;  // 0..3
  int h = bh & 7;
  const ushort* A = Y + (size_t)bh * DKc * Dd;
  const ushort* B = WvT + (size_t)(h * DVc + bn * 128) * Dd;
  int wave = threadIdx.x >> 6;
  int lane = threadIdx.x & 63;
  int wm = wave >> 1, wn = wave & 1;
  int lrow = lane & 15;
  int quad = lane >> 4;
  int rowInChunk = lane >> 2;
  int kElem = (lane & 3) * 8;

  f32x4 acc[4][4] = {};
  int kk0 = ks * 512;
  for (int kk = kk0; kk < kk0 + 512; kk += 32) {
#pragma unroll
    for (int r = 0; r < 2; ++r) {
      int chunk = wave * 2 + r;
      int arow = chunk * 16 + rowInChunk;
      const ushort* ga = A + (size_t)arow * Dd + kk + kElem;
      const ushort* gb = B + (size_t)arow * Dd + kk + kElem;
      __builtin_amdgcn_global_load_lds((__attribute__((address_space(1))) void*)ga,
                                       (__attribute__((address_space(3))) void*)(As + chunk * 512),
                                       16, 0, 0);
      __builtin_amdgcn_global_load_lds((__attribute__((address_space(1))) void*)gb,
                                       (__attribute__((address_space(3))) void*)(Bs + chunk * 512),
                                       16, 0, 0);
    }
    __syncthreads();
    bf16x8 af[4], bfr[4];
#pragma unroll
    for (int i = 0; i < 4; ++i) af[i] = *(const bf16x8*)(As + (wm * 64 + i * 16 + lrow) * 32 + quad * 8);
#pragma unroll
    for (int j = 0; j < 4; ++j) bfr[j] = *(const bf16x8*)(Bs + (wn * 64 + j * 16 + lrow) * 32 + quad * 8);
#pragma unroll
    for (int i = 0; i < 4; ++i)
#pragma unroll
      for (int j = 0; j < 4; ++j)
        acc[i][j] = __builtin_amdgcn_mfma_f32_16x16x32_bf16(af[i], bfr[j], acc[i][j], 0, 0, 0);
    __syncthreads();
  }

  float* Sp = Spart + ((size_t)ks * NBH + bh) * (DKc * DVc);
#pragma unroll
  for (int i = 0; i < 4; ++i) {
    int row0 = wm * 64 + i * 16 + quad * 4;  // kd
#pragma unroll
    for (int j = 0; j < 4; ++j) {
      int col = bn * 128 + wn * 64 + j * 16 + lrow;  // vv
#pragma unroll
      for (int rg = 0; rg < 4; ++rg)
        Sp[(size_t)(row0 + rg) * DVc + col] = acc[i][j][rg];
    }
  }
}

// ------------- out = S0*eBtot + sum_ks Spart -------------
__global__ __launch_bounds__(256) void reduce_kernel(const float* __restrict__ Spart,
                                                     const float* __restrict__ eBtot,
                                                     const float* __restrict__ S0,
                                                     float* __restrict__ out) {
  int i4 = blockIdx.x * 256 + threadIdx.x;
  int idx = i4 * 4;
  int bh = idx >> 15;
  int kd = (idx >> 8) & 127;
  float e = eBtot[bh * DKc + kd];
  float4 a = ((const float4*)S0)[i4];
  float4 p0 = ((const float4*)Spart)[i4];
  float4 p1 = ((const float4*)Spart)[i4 + 262144];
  float4 p2 = ((const float4*)Spart)[i4 + 524288];
  float4 p3 = ((const float4*)Spart)[i4 + 786432];
  float4 r;
  r.x = a.x * e + p0.x + p1.x + p2.x + p3.x;
  r.y = a.y * e + p0.y + p1.y + p2.y + p3.y;
  r.z = a.z * e + p0.z + p1.z + p2.z + p3.z;
  r.w = a.w * e + p0.w + p1.w + p2.w + p3.w;
  ((float4*)out)[i4] = r;
}

// ------------- chunk gate sums: L[bh][n][kd] = sum_c logsig(g1@Wg2col + b)/GLN -------------
__global__ __launch_bounds__(128) void chunksum_kernel(const float* __restrict__ g1,
                                                       const float* __restrict__ Wg2,
                                                       const float* __restrict__ bg2,
                                                       float* __restrict__ L) {
  int n = blockIdx.x, bh = blockIdx.y;
  int b = bh >> 3, h = bh & 7;
  int t = threadIdx.x;  // kd
  int kdg = h * DKc + t;
  int trow = b * Tt + n * CHUNKc;
  __shared__ float g1s[CHUNKc * 16];
#pragma unroll
  for (int i = 0; i < 8; ++i) {
    int flat = i * 128 + t;
    int c = flat >> 4, r = flat & 15;
    g1s[flat] = g1[(size_t)(trow + c) * 128 + r];
  }
  float wc[16];
#pragma unroll
  for (int r = 0; r < 16; ++r) wc[r] = Wg2[r * KDIM + kdg];
  float bias = bg2[kdg];
  __syncthreads();
  float sum = 0.f;
  for (int c = 0; c < CHUNKc; ++c) {
    float dot = bias;
#pragma unroll
    for (int r = 0; r < 16; ++r) dot = fmaf(g1s[c * 16 + r], wc[r], dot);
    sum += logsig(dot) * (1.0f / GLNf);
  }
  L[((size_t)bh * NCHUNK + n) * DKc + t] = sum;
}

// ------------- weights: kwT[bh][kd][t] = bf16(k * exp(Btot - B_t)) in place; eBtot -------------
__global__ __launch_bounds__(128) void weight_kernel(const float* __restrict__ g1,
                                                     const float* __restrict__ Wg2,
                                                     const float* __restrict__ bg2,
                                                     const float* __restrict__ L,
                                                     ushort* __restrict__ kwT,
                                                     float* __restrict__ eBtot) {
  int n = blockIdx.x, bh = blockIdx.y;
  int b = bh >> 3, h = bh & 7;
  int t = threadIdx.x;  // kd
  int kdg = h * DKc + t;
  int trow = b * Tt + n * CHUNKc;
  __shared__ float g1s[CHUNKc * 16];
#pragma unroll
  for (int i = 0; i < 8; ++i) {
    int flat = i * 128 + t;
    int c = flat >> 4, r = flat & 15;
    g1s[flat] = g1[(size_t)(trow + c) * 128 + r];
  }
  float wc[16];
#pragma unroll
  for (int r = 0; r < 16; ++r) wc[r] = Wg2[r * KDIM + kdg];
  float bias = bg2[kdg];

  float suffix = 0.f, Ln = 0.f, Btot = 0.f;
#pragma unroll
  for (int m = 0; m < NCHUNK; ++m) {
    float Lm = L[((size_t)bh * NCHUNK + m) * DKc + t];
    if (m > n) suffix += Lm;
    if (m == n) Ln = Lm;
    Btot += Lm;
  }
  if (n == 0) eBtot[bh * DKc + t] = __expf(Btot);
  __syncthreads();

  float run = 0.f;
  size_t obase = ((size_t)bh * DKc + t) * (size_t)Tt + (size_t)n * CHUNKc;
  for (int cg = 0; cg < 8; ++cg) {
    ushort8v kw8;
    ushort8v k8 = *(const ushort8v*)(kwT + obase + cg * 8);
#pragma unroll
    for (int j = 0; j < 8; ++j) {
      int c = cg * 8 + j;
      float dot = bias;
#pragma unroll
      for (int r = 0; r < 16; ++r) dot = fmaf(g1s[c * 16 + r], wc[r], dot);
      run += logsig(dot) * (1.0f / GLNf);
      float w = __expf(suffix + Ln - run);  // exponent <= 0 always
      kw8[j] = f2bf(bf2f(k8[j]) * w);
    }
    *(ushort8v*)(kwT + obase + cg * 8) = kw8;
  }
}

extern "C" void kernel_launch(void* const* d_in, const int* in_sizes, int n_in,
                              void* d_out, int out_size, void* d_ws, size_t ws_size,
                              hipStream_t stream) {
  const float* seg = (const float*)d_in[0];
  const float* norm_w = (const float*)d_in[1];
  const float* Wk = (const float*)d_in[2];
  const float* Wv = (const float*)d_in[3];
  const float* Wg1 = (const float*)d_in[4];
  const float* Wg2 = (const float*)d_in[5];
  const float* bg2 = (const float*)d_in[6];
  const float* S0 = (const float*)d_in[7];
  float* out = (float*)d_out;
  char* ws = (char*)d_ws;

  // ---- workspace 93.65 MiB (proven available R6/R7) ----
  // regA 32MiB: xb bf16[8192][2048] -> (dead after gemm_kg + transpose_x) Y bf16[32][128][2048]
  // regB 32MiB: xT bf16[4][2048][2048]
  // regD 16MiB: kT bf16[32][128][2048] -> kwT (in-place RMW) -> (dead after gemm_y)
  //             Spart f32[4][32][128][256]
  // regC 12.5MiB: W_allT bf16[3200][2048]; then Lbuf f32[32][32][128], eBtot f32[32][128]
  // d_out: g1 f32[8192][128] (dead before reduce writes d_out)
  char* regA = ws;
  char* regB = ws + (size_t)32 * 1024 * 1024;
  char* regD = ws + (size_t)64 * 1024 * 1024;
  char* regC = ws + (size_t)80 * 1024 * 1024;
  float* Lbuf = (float*)(regC + 13107200);
  float* eBtot = (float*)(regC + 13107200 + 524288);

  ushort* xb = (ushort*)regA;
  ushort* Y = (ushort*)regA;                   // after xb dead
  ushort* xT = (ushort*)regB;
  ushort* kwT = (ushort*)regD;
  float* Spart = (float*)regD;                 // after kwT dead (post gemm_y)
  ushort* Wall = (ushort*)regC;
  ushort* Wallk = Wall + (size_t)2048 * 2048;  // rows 2048.. = [Wk^T ; Wg1^T]
  float* g1buf = (float*)d_out;

  rmsnorm_kernel<<<Mrows, 256, 0, stream>>>(seg, norm_w, xb);
  transpose_all_kernel<<<dim3(64, 100), 256, 0, stream>>>(Wv, Wk, Wg1, Wall);
  transpose_x_kernel<<<dim3(32, 32, 4), 256, 0, stream>>>(xb, xT);
  gemm_kg_kernel<<<576, 256, 0, stream>>>(xb, Wallk, kwT, g1buf);
  chunksum_kernel<<<dim3(NCHUNK, NBH), 128, 0, stream>>>(g1buf, Wg2, bg2, Lbuf);
  weight_kernel<<<dim3(NCHUNK, NBH), 128, 0, stream>>>(g1buf, Wg2, bg2, Lbuf, kwT, eBtot);
  gemm_y_kernel<<<dim3(16, NBH), 256, 0, stream>>>(kwT, xT, Y);
  gemm_out_sk_kernel<<<dim3(2, NBH, 4), 256, 0, stream>>>(Y, Wall, Spart);
  reduce_kernel<<<1024, 256, 0, stream>>>(Spart, eBtot, S0, out);
}

// Round 9
// 343.415 us; speedup vs baseline: 2.0444x; 1.0137x over previous
//
#include <hip/hip_runtime.h>
#include <math.h>

#define Hh 8
#define DKc 128
#define DVc 256
#define CHUNKc 64
#define GLNf 16.0f
#define EPSf 1e-5f

#define Bb 4
#define Tt 2048
#define Dd 2048
#define KDIM 1024
#define VDIM 2048
#define Mrows 8192
#define NCHUNK 32
#define NBH 32

typedef short bf16x8 __attribute__((ext_vector_type(8)));
typedef float f32x4 __attribute__((ext_vector_type(4)));
typedef ushort ushort8v __attribute__((ext_vector_type(8)));

__device__ inline ushort f2bf(float f) {
  unsigned u = __float_as_uint(f);
  unsigned r = (u + 0x7fffu + ((u >> 16) & 1u)) >> 16;
  return (ushort)r;
}
__device__ inline float bf2f(ushort u) {
  return __uint_as_float(((unsigned)u) << 16);
}
// log_sigmoid(g) = min(g,0) - log(1 + exp(-|g|)); branch-free, hw v_exp/v_log.
__device__ inline float logsig(float g) {
  return fminf(g, 0.f) - __logf(1.f + __expf(-fabsf(g)));
}

// ---------------- RMSNorm + bf16 cast: one block per row ----------------
__global__ __launch_bounds__(256) void rmsnorm_kernel(const float* __restrict__ seg,
                                                      const float* __restrict__ norm_w,
                                                      ushort* __restrict__ xb) {
  int row = blockIdx.x;
  int t = threadIdx.x;
  const float4* p = (const float4*)(seg + (size_t)row * Dd);
  float4 a = p[t];
  float4 b = p[t + 256];
  float ss = a.x * a.x + a.y * a.y + a.z * a.z + a.w * a.w +
             b.x * b.x + b.y * b.y + b.z * b.z + b.w * b.w;
#pragma unroll
  for (int off = 32; off > 0; off >>= 1) ss += __shfl_down(ss, off);
  __shared__ float red[4];
  if ((t & 63) == 0) red[t >> 6] = ss;
  __syncthreads();
  float tot = red[0] + red[1] + red[2] + red[3];
  float scale = rsqrtf(tot * (1.0f / (float)Dd) + EPSf);
  const float4* w4 = (const float4*)norm_w;
  float4 wa = w4[t], wb = w4[t + 256];
  ushort4 oa, ob;
  oa.x = f2bf(a.x * scale * wa.x);
  oa.y = f2bf(a.y * scale * wa.y);
  oa.z = f2bf(a.z * scale * wa.z);
  oa.w = f2bf(a.w * scale * wa.w);
  ob.x = f2bf(b.x * scale * wb.x);
  ob.y = f2bf(b.y * scale * wb.y);
  ob.z = f2bf(b.z * scale * wb.z);
  ob.w = f2bf(b.w * scale * wb.w);
  ushort4* o4 = (ushort4*)(xb + (size_t)row * Dd);
  o4[t] = oa;
  o4[t + 256] = ob;
}

// --- fused transpose: W_allT[3200][2048] = [Wv^T(2048) ; Wk^T(1024) ; Wg1^T pad(128)] ---
__global__ __launch_bounds__(256) void transpose_all_kernel(const float* __restrict__ Wv,
                                                            const float* __restrict__ Wk,
                                                            const float* __restrict__ Wg1,
                                                            ushort* __restrict__ Wall) {
  const int K = 2048;
  __shared__ float tile[32][33];
  int k0 = blockIdx.x * 32;
  int n0 = blockIdx.y * 32;
  const float* src;
  int N, stride, nb;
  if (n0 < 2048) {
    src = Wv; N = 2048; stride = 2048; nb = n0;
  } else if (n0 < 3072) {
    src = Wk; N = 1024; stride = 1024; nb = n0 - 2048;
  } else {
    src = Wg1; N = 16; stride = 16; nb = n0 - 3072;
  }
  int tx = threadIdx.x & 31;
  int ty = threadIdx.x >> 5;
#pragma unroll
  for (int i = 0; i < 32; i += 8) {
    int k = k0 + ty + i;
    int n = nb + tx;
    tile[ty + i][tx] = (n < N) ? src[(size_t)k * stride + n] : 0.0f;
  }
  __syncthreads();
#pragma unroll
  for (int i = 0; i < 32; i += 8) {
    Wall[(size_t)(n0 + ty + i) * K + k0 + tx] = f2bf(tile[tx][ty + i]);
  }
}

// --- per-batch bf16 transpose v2: 64x64 tiles, ushort4 global, stride-65 LDS ---
__global__ __launch_bounds__(256) void transpose_x_kernel(const ushort* __restrict__ xb,
                                                          ushort* __restrict__ xT) {
  __shared__ ushort tile[64 * 65];
  int b = blockIdx.z;
  int t0 = blockIdx.x * 64;
  int d0 = blockIdx.y * 64;
  int tx = threadIdx.x & 15;   // d quad
  int ty = threadIdx.x >> 4;   // 0..15
#pragma unroll
  for (int i = 0; i < 4; ++i) {
    int t = i * 16 + ty;
    ushort4 v = *(const ushort4*)(xb + ((size_t)b * Tt + t0 + t) * Dd + d0 + tx * 4);
    tile[t * 65 + tx * 4 + 0] = v.x;
    tile[t * 65 + tx * 4 + 1] = v.y;
    tile[t * 65 + tx * 4 + 2] = v.z;
    tile[t * 65 + tx * 4 + 3] = v.w;
  }
  __syncthreads();
  int tw = threadIdx.x & 15;   // t quad
  int dw = threadIdx.x >> 4;   // 0..15
#pragma unroll
  for (int j = 0; j < 4; ++j) {
    int d = j * 16 + dw;
    ushort4 o;
    o.x = tile[(tw * 4 + 0) * 65 + d];
    o.y = tile[(tw * 4 + 1) * 65 + d];
    o.z = tile[(tw * 4 + 2) * 65 + d];
    o.w = tile[(tw * 4 + 3) * 65 + d];
    *(ushort4*)(xT + ((size_t)b * Dd + d0 + d) * Tt + t0 + tw * 4) = o;
  }
}

// ------- GEMM1: xb[8192][2048] @ Wallk[1152][2048]^T; bn<8 -> kT[bh][kd][t], bn==8 -> g1 -------
// XCD-aware 1D grid 576: idx%8 == bm%8, so all 9 bn-blocks sharing an A-tile land on
// the same XCD (round-robin dispatch heuristic); g1 tile (bn=8) interleaved (no tail).
__global__ __launch_bounds__(256) void gemm_kg_kernel(const ushort* __restrict__ A,
                                                      const ushort* __restrict__ Wallk,
                                                      ushort* __restrict__ kT,
                                                      float* __restrict__ g1) {
  __shared__ __align__(16) ushort As[128 * 32];
  __shared__ __align__(16) ushort Bs[128 * 32];
  int q = blockIdx.x >> 3;             // 0..71
  int bm = (blockIdx.x & 7) + 8 * (q / 9);
  int bn = q % 9;
  int wave = threadIdx.x >> 6;
  int lane = threadIdx.x & 63;
  int wm = wave >> 1, wn = wave & 1;
  int lrow = lane & 15;
  int quad = lane >> 4;
  int rowInChunk = lane >> 2;
  int kElem = (lane & 3) * 8;

  f32x4 acc[4][4] = {};
  for (int kk = 0; kk < Dd; kk += 32) {
#pragma unroll
    for (int r = 0; r < 2; ++r) {
      int chunk = wave * 2 + r;
      int arow = chunk * 16 + rowInChunk;
      const ushort* ga = A + ((size_t)(bm * 128 + arow)) * Dd + kk + kElem;
      const ushort* gb = Wallk + ((size_t)(bn * 128 + arow)) * Dd + kk + kElem;
      __builtin_amdgcn_global_load_lds((__attribute__((address_space(1))) void*)ga,
                                       (__attribute__((address_space(3))) void*)(As + chunk * 512),
                                       16, 0, 0);
      __builtin_amdgcn_global_load_lds((__attribute__((address_space(1))) void*)gb,
                                       (__attribute__((address_space(3))) void*)(Bs + chunk * 512),
                                       16, 0, 0);
    }
    __syncthreads();
    bf16x8 af[4], bfr[4];
#pragma unroll
    for (int i = 0; i < 4; ++i) af[i] = *(const bf16x8*)(As + (wm * 64 + i * 16 + lrow) * 32 + quad * 8);
#pragma unroll
    for (int j = 0; j < 4; ++j) bfr[j] = *(const bf16x8*)(Bs + (wn * 64 + j * 16 + lrow) * 32 + quad * 8);
#pragma unroll
    for (int i = 0; i < 4; ++i)
#pragma unroll
      for (int j = 0; j < 4; ++j)
        acc[i][j] = __builtin_amdgcn_mfma_f32_16x16x32_bf16(af[i], bfr[j], acc[i][j], 0, 0, 0);
    __syncthreads();
  }

#pragma unroll
  for (int i = 0; i < 4; ++i) {
    int m0 = bm * 128 + wm * 64 + i * 16 + quad * 4;
    int b = m0 >> 11, tloc = m0 & 2047;
#pragma unroll
    for (int j = 0; j < 4; ++j) {
      int col = bn * 128 + wn * 64 + j * 16 + lrow;
      if (bn < 8) {  // k: kT[bh][kd][t]
        int h = col >> 7, kd = col & 127;
        ushort4 o;
        o.x = f2bf(acc[i][j][0]);
        o.y = f2bf(acc[i][j][1]);
        o.z = f2bf(acc[i][j][2]);
        o.w = f2bf(acc[i][j][3]);
        *(ushort4*)(kT + ((size_t)((b * 8 + h) * 128 + kd)) * 2048 + tloc) = o;
      } else {  // g1 fp32 [8192][128]
        int cg = col - 1024;
#pragma unroll
        for (int rg = 0; rg < 4; ++rg)
          g1[(size_t)(m0 + rg) * 128 + cg] = acc[i][j][rg];
      }
    }
  }
}

// ------- GEMM2: Y[bh][kd][d] = kwT[bh](128 x 2048_t) @ xT[b](2048_d x 2048_t)^T -------
// XCD swizzle: idx%8 == bh%8 — the 16 bn-blocks sharing one kwT A-tile colocate.
__global__ __launch_bounds__(256) void gemm_y_kernel(const ushort* __restrict__ kwT,
                                                     const ushort* __restrict__ xT,
                                                     ushort* __restrict__ Y) {
  __shared__ __align__(16) ushort As[128 * 32];
  __shared__ __align__(16) ushort Bs[128 * 32];
  int q = blockIdx.x >> 3;             // 0..63
  int bn = q & 15;                     // d tile 0..15
  int bh = (blockIdx.x & 7) + 8 * (q >> 4);
  int b = bh >> 3;
  const ushort* A = kwT + (size_t)bh * DKc * Tt;
  const ushort* B = xT + (size_t)b * Dd * Tt;
  int wave = threadIdx.x >> 6;
  int lane = threadIdx.x & 63;
  int wm = wave >> 1, wn = wave & 1;
  int lrow = lane & 15;
  int quad = lane >> 4;
  int rowInChunk = lane >> 2;
  int kElem = (lane & 3) * 8;

  f32x4 acc[4][4] = {};
  for (int kk = 0; kk < Tt; kk += 32) {
#pragma unroll
    for (int r = 0; r < 2; ++r) {
      int chunk = wave * 2 + r;
      int arow = chunk * 16 + rowInChunk;
      const ushort* ga = A + (size_t)arow * Tt + kk + kElem;
      const ushort* gb = B + ((size_t)(bn * 128 + arow)) * Tt + kk + kElem;
      __builtin_amdgcn_global_load_lds((__attribute__((address_space(1))) void*)ga,
                                       (__attribute__((address_space(3))) void*)(As + chunk * 512),
                                       16, 0, 0);
      __builtin_amdgcn_global_load_lds((__attribute__((address_space(1))) void*)gb,
                                       (__attribute__((address_space(3))) void*)(Bs + chunk * 512),
                                       16, 0, 0);
    }
    __syncthreads();
    bf16x8 af[4], bfr[4];
#pragma unroll
    for (int i = 0; i < 4; ++i) af[i] = *(const bf16x8*)(As + (wm * 64 + i * 16 + lrow) * 32 + quad * 8);
#pragma unroll
    for (int j = 0; j < 4; ++j) bfr[j] = *(const bf16x8*)(Bs + (wn * 64 + j * 16 + lrow) * 32 + quad * 8);
#pragma unroll
    for (int i = 0; i < 4; ++i)
#pragma unroll
      for (int j = 0; j < 4; ++j)
        acc[i][j] = __builtin_amdgcn_mfma_f32_16x16x32_bf16(af[i], bfr[j], acc[i][j], 0, 0, 0);
    __syncthreads();
  }

#pragma unroll
  for (int i = 0; i < 4; ++i) {
    int row0 = wm * 64 + i * 16 + quad * 4;  // kd
#pragma unroll
    for (int j = 0; j < 4; ++j) {
      int col = bn * 128 + wn * 64 + j * 16 + lrow;  // d
#pragma unroll
      for (int rg = 0; rg < 4; ++rg)
        Y[((size_t)bh * DKc + row0 + rg) * Dd + col] = f2bf(acc[i][j][rg]);
    }
  }
}

// ------- GEMM3 split-K: Spart[ks][bh] = Y[bh](128 x 512_d) @ WvT_h(256 x 512_d)^T -------
// XCD swizzle: idx%8 == bh%8 == h — colocates Y A-tile users AND all batches sharing WvT_h.
__global__ __launch_bounds__(256) void gemm_out_sk_kernel(const ushort* __restrict__ Y,
                                                          const ushort* __restrict__ WvT,
                                                          float* __restrict__ Spart) {
  __shared__ __align__(16) ushort As[128 * 32];
  __shared__ __align__(16) ushort Bs[128 * 32];
  int q = blockIdx.x >> 3;             // 0..31
  int inner = q & 7;
  int bn = inner >> 2;                 // vv tile 0..1
  int ks = inner & 3;                  // split-K 0..3
  int bh = (blockIdx.x & 7) + 8 * (q >> 3);
  int h = bh & 7;
  const ushort* A = Y + (size_t)bh * DKc * Dd;
  const ushort* B = WvT + (size_t)(h * DVc + bn * 128) * Dd;
  int wave = threadIdx.x >> 6;
  int lane = threadIdx.x & 63;
  int wm = wave >> 1, wn = wave & 1;
  int lrow = lane & 15;
  int quad = lane >> 4;
  int rowInChunk = lane >> 2;
  int kElem = (lane & 3) * 8;

  f32x4 acc[4][4] = {};
  int kk0 = ks * 512;
  for (int kk = kk0; kk < kk0 + 512; kk += 32) {
#pragma unroll
    for (int r = 0; r < 2; ++r) {
      int chunk = wave * 2 + r;
      int arow = chunk * 16 + rowInChunk;
      const ushort* ga = A + (size_t)arow * Dd + kk + kElem;
      const ushort* gb = B + (size_t)arow * Dd + kk + kElem;
      __builtin_amdgcn_global_load_lds((__attribute__((address_space(1))) void*)ga,
                                       (__attribute__((address_space(3))) void*)(As + chunk * 512),
                                       16, 0, 0);
      __builtin_amdgcn_global_load_lds((__attribute__((address_space(1))) void*)gb,
                                       (__attribute__((address_space(3))) void*)(Bs + chunk * 512),
                                       16, 0, 0);
    }
    __syncthreads();
    bf16x8 af[4], bfr[4];
#pragma unroll
    for (int i = 0; i < 4; ++i) af[i] = *(const bf16x8*)(As + (wm * 64 + i * 16 + lrow) * 32 + quad * 8);
#pragma unroll
    for (int j = 0; j < 4; ++j) bfr[j] = *(const bf16x8*)(Bs + (wn * 64 + j * 16 + lrow) * 32 + quad * 8);
#pragma unroll
    for (int i = 0; i < 4; ++i)
#pragma unroll
      for (int j = 0; j < 4; ++j)
        acc[i][j] = __builtin_amdgcn_mfma_f32_16x16x32_bf16(af[i], bfr[j], acc[i][j], 0, 0, 0);
    __syncthreads();
  }

  float* Sp = Spart + ((size_t)ks * NBH + bh) * (DKc * DVc);
#pragma unroll
  for (int i = 0; i < 4; ++i) {
    int row0 = wm * 64 + i * 16 + quad * 4;  // kd
#pragma unroll
    for (int j = 0; j < 4; ++j) {
      int col = bn * 128 + wn * 64 + j * 16 + lrow;  // vv
#pragma unroll
      for (int rg = 0; rg < 4; ++rg)
        Sp[(size_t)(row0 + rg) * DVc + col] = acc[i][j][rg];
    }
  }
}

// ------------- out = S0*eBtot + sum_ks Spart -------------
__global__ __launch_bounds__(256) void reduce_kernel(const float* __restrict__ Spart,
                                                     const float* __restrict__ eBtot,
                                                     const float* __restrict__ S0,
                                                     float* __restrict__ out) {
  int i4 = blockIdx.x * 256 + threadIdx.x;
  int idx = i4 * 4;
  int bh = idx >> 15;
  int kd = (idx >> 8) & 127;
  float e = eBtot[bh * DKc + kd];
  float4 a = ((const float4*)S0)[i4];
  float4 p0 = ((const float4*)Spart)[i4];
  float4 p1 = ((const float4*)Spart)[i4 + 262144];
  float4 p2 = ((const float4*)Spart)[i4 + 524288];
  float4 p3 = ((const float4*)Spart)[i4 + 786432];
  float4 r;
  r.x = a.x * e + p0.x + p1.x + p2.x + p3.x;
  r.y = a.y * e + p0.y + p1.y + p2.y + p3.y;
  r.z = a.z * e + p0.z + p1.z + p2.z + p3.z;
  r.w = a.w * e + p0.w + p1.w + p2.w + p3.w;
  ((float4*)out)[i4] = r;
}

// ------------- chunk gate sums: L[bh][n][kd] = sum_c logsig(g1@Wg2col + b)/GLN -------------
__global__ __launch_bounds__(128) void chunksum_kernel(const float* __restrict__ g1,
                                                       const float* __restrict__ Wg2,
                                                       const float* __restrict__ bg2,
                                                       float* __restrict__ L) {
  int n = blockIdx.x, bh = blockIdx.y;
  int b = bh >> 3, h = bh & 7;
  int t = threadIdx.x;  // kd
  int kdg = h * DKc + t;
  int trow = b * Tt + n * CHUNKc;
  __shared__ float g1s[CHUNKc * 16];
#pragma unroll
  for (int i = 0; i < 8; ++i) {
    int flat = i * 128 + t;
    int c = flat >> 4, r = flat & 15;
    g1s[flat] = g1[(size_t)(trow + c) * 128 + r];
  }
  float wc[16];
#pragma unroll
  for (int r = 0; r < 16; ++r) wc[r] = Wg2[r * KDIM + kdg];
  float bias = bg2[kdg];
  __syncthreads();
  float sum = 0.f;
  for (int c = 0; c < CHUNKc; ++c) {
    float dot = bias;
#pragma unroll
    for (int r = 0; r < 16; ++r) dot = fmaf(g1s[c * 16 + r], wc[r], dot);
    sum += logsig(dot) * (1.0f / GLNf);
  }
  L[((size_t)bh * NCHUNK + n) * DKc + t] = sum;
}

// ------------- weights: kwT[bh][kd][t] = bf16(k * exp(Btot - B_t)) in place; eBtot -------------
__global__ __launch_bounds__(128) void weight_kernel(const float* __restrict__ g1,
                                                     const float* __restrict__ Wg2,
                                                     const float* __restrict__ bg2,
                                                     const float* __restrict__ L,
                                                     ushort* __restrict__ kwT,
                                                     float* __restrict__ eBtot) {
  int n = blockIdx.x, bh = blockIdx.y;
  int b = bh >> 3, h = bh & 7;
  int t = threadIdx.x;  // kd
  int kdg = h * DKc + t;
  int trow = b * Tt + n * CHUNKc;
  __shared__ float g1s[CHUNKc * 16];
#pragma unroll
  for (int i = 0; i < 8; ++i) {
    int flat = i * 128 + t;
    int c = flat >> 4, r = flat & 15;
    g1s[flat] = g1[(size_t)(trow + c) * 128 + r];
  }
  float wc[16];
#pragma unroll
  for (int r = 0; r < 16; ++r) wc[r] = Wg2[r * KDIM + kdg];
  float bias = bg2[kdg];

  float suffix = 0.f, Ln = 0.f, Btot = 0.f;
#pragma unroll
  for (int m = 0; m < NCHUNK; ++m) {
    float Lm = L[((size_t)bh * NCHUNK + m) * DKc + t];
    if (m > n) suffix += Lm;
    if (m == n) Ln = Lm;
    Btot += Lm;
  }
  if (n == 0) eBtot[bh * DKc + t] = __expf(Btot);
  __syncthreads();

  float run = 0.f;
  size_t obase = ((size_t)bh * DKc + t) * (size_t)Tt + (size_t)n * CHUNKc;
  for (int cg = 0; cg < 8; ++cg) {
    ushort8v kw8;
    ushort8v k8 = *(const ushort8v*)(kwT + obase + cg * 8);
#pragma unroll
    for (int j = 0; j < 8; ++j) {
      int c = cg * 8 + j;
      float dot = bias;
#pragma unroll
      for (int r = 0; r < 16; ++r) dot = fmaf(g1s[c * 16 + r], wc[r], dot);
      run += logsig(dot) * (1.0f / GLNf);
      float w = __expf(suffix + Ln - run);  // exponent <= 0 always
      kw8[j] = f2bf(bf2f(k8[j]) * w);
    }
    *(ushort8v*)(kwT + obase + cg * 8) = kw8;
  }
}

extern "C" void kernel_launch(void* const* d_in, const int* in_sizes, int n_in,
                              void* d_out, int out_size, void* d_ws, size_t ws_size,
                              hipStream_t stream) {
  const float* seg = (const float*)d_in[0];
  const float* norm_w = (const float*)d_in[1];
  const float* Wk = (const float*)d_in[2];
  const float* Wv = (const float*)d_in[3];
  const float* Wg1 = (const float*)d_in[4];
  const float* Wg2 = (const float*)d_in[5];
  const float* bg2 = (const float*)d_in[6];
  const float* S0 = (const float*)d_in[7];
  float* out = (float*)d_out;
  char* ws = (char*)d_ws;

  // ---- workspace 93.65 MiB (proven available R6/R7/R8) ----
  // regA 32MiB: xb bf16[8192][2048] -> (dead after gemm_kg + transpose_x) Y bf16[32][128][2048]
  // regB 32MiB: xT bf16[4][2048][2048]
  // regD 16MiB: kT bf16[32][128][2048] -> kwT (in-place RMW) -> (dead after gemm_y)
  //             Spart f32[4][32][128][256]
  // regC 12.5MiB: W_allT bf16[3200][2048]; then Lbuf f32[32][32][128], eBtot f32[32][128]
  // d_out: g1 f32[8192][128] (dead before reduce writes d_out)
  char* regA = ws;
  char* regB = ws + (size_t)32 * 1024 * 1024;
  char* regD = ws + (size_t)64 * 1024 * 1024;
  char* regC = ws + (size_t)80 * 1024 * 1024;
  float* Lbuf = (float*)(regC + 13107200);
  float* eBtot = (float*)(regC + 13107200 + 524288);

  ushort* xb = (ushort*)regA;
  ushort* Y = (ushort*)regA;                   // after xb dead
  ushort* xT = (ushort*)regB;
  ushort* kwT = (ushort*)regD;
  float* Spart = (float*)regD;                 // after kwT dead (post gemm_y)
  ushort* Wall = (ushort*)regC;
  ushort* Wallk = Wall + (size_t)2048 * 2048;  // rows 2048.. = [Wk^T ; Wg1^T]
  float* g1buf = (float*)d_out;

  rmsnorm_kernel<<<Mrows, 256, 0, stream>>>(seg, norm_w, xb);
  transpose_all_kernel<<<dim3(64, 100), 256, 0, stream>>>(Wv, Wk, Wg1, Wall);
  transpose_x_kernel<<<dim3(32, 32, 4), 256, 0, stream>>>(xb, xT);
  gemm_kg_kernel<<<576, 256, 0, stream>>>(xb, Wallk, kwT, g1buf);
  chunksum_kernel<<<dim3(NCHUNK, NBH), 128, 0, stream>>>(g1buf, Wg2, bg2, Lbuf);
  weight_kernel<<<dim3(NCHUNK, NBH), 128, 0, stream>>>(g1buf, Wg2, bg2, Lbuf, kwT, eBtot);
  gemm_y_kernel<<<512, 256, 0, stream>>>(kwT, xT, Y);
  gemm_out_sk_kernel<<<256, 256, 0, stream>>>(Y, Wall, Spart);
  reduce_kernel<<<1024, 256, 0, stream>>>(Spart, eBtot, S0, out);
}

// Round 10
// 340.388 us; speedup vs baseline: 2.0626x; 1.0089x over previous
//
#include <hip/hip_runtime.h>
#include <math.h>

#define Hh 8
#define DKc 128
#define DVc 256
#define CHUNKc 64
#define GLNf 16.0f
#define EPSf 1e-5f

#define Bb 4
#define Tt 2048
#define Dd 2048
#define KDIM 1024
#define VDIM 2048
#define Mrows 8192
#define NCHUNK 32
#define NBH 32

typedef short bf16x8 __attribute__((ext_vector_type(8)));
typedef float f32x4 __attribute__((ext_vector_type(4)));
typedef ushort ushort8v __attribute__((ext_vector_type(8)));

__device__ inline ushort f2bf(float f) {
  unsigned u = __float_as_uint(f);
  unsigned r = (u + 0x7fffu + ((u >> 16) & 1u)) >> 16;
  return (ushort)r;
}
__device__ inline float bf2f(ushort u) {
  return __uint_as_float(((unsigned)u) << 16);
}
// log_sigmoid(g) = min(g,0) - log(1 + exp(-|g|)); branch-free, hw v_exp/v_log.
__device__ inline float logsig(float g) {
  return fminf(g, 0.f) - __logf(1.f + __expf(-fabsf(g)));
}

// ---------------- RMSNorm + bf16 cast: one block per row ----------------
__global__ __launch_bounds__(256) void rmsnorm_kernel(const float* __restrict__ seg,
                                                      const float* __restrict__ norm_w,
                                                      ushort* __restrict__ xb) {
  int row = blockIdx.x;
  int t = threadIdx.x;
  const float4* p = (const float4*)(seg + (size_t)row * Dd);
  float4 a = p[t];
  float4 b = p[t + 256];
  float ss = a.x * a.x + a.y * a.y + a.z * a.z + a.w * a.w +
             b.x * b.x + b.y * b.y + b.z * b.z + b.w * b.w;
#pragma unroll
  for (int off = 32; off > 0; off >>= 1) ss += __shfl_down(ss, off);
  __shared__ float red[4];
  if ((t & 63) == 0) red[t >> 6] = ss;
  __syncthreads();
  float tot = red[0] + red[1] + red[2] + red[3];
  float scale = rsqrtf(tot * (1.0f / (float)Dd) + EPSf);
  const float4* w4 = (const float4*)norm_w;
  float4 wa = w4[t], wb = w4[t + 256];
  ushort4 oa, ob;
  oa.x = f2bf(a.x * scale * wa.x);
  oa.y = f2bf(a.y * scale * wa.y);
  oa.z = f2bf(a.z * scale * wa.z);
  oa.w = f2bf(a.w * scale * wa.w);
  ob.x = f2bf(b.x * scale * wb.x);
  ob.y = f2bf(b.y * scale * wb.y);
  ob.z = f2bf(b.z * scale * wb.z);
  ob.w = f2bf(b.w * scale * wb.w);
  ushort4* o4 = (ushort4*)(xb + (size_t)row * Dd);
  o4[t] = oa;
  o4[t + 256] = ob;
}

// --- fused transpose: W_allT[3200][2048] = [Wv^T(2048) ; Wk^T(1024) ; Wg1^T pad(128)] ---
__global__ __launch_bounds__(256) void transpose_all_kernel(const float* __restrict__ Wv,
                                                            const float* __restrict__ Wk,
                                                            const float* __restrict__ Wg1,
                                                            ushort* __restrict__ Wall) {
  const int K = 2048;
  __shared__ float tile[32][33];
  int k0 = blockIdx.x * 32;
  int n0 = blockIdx.y * 32;
  const float* src;
  int N, stride, nb;
  if (n0 < 2048) {
    src = Wv; N = 2048; stride = 2048; nb = n0;
  } else if (n0 < 3072) {
    src = Wk; N = 1024; stride = 1024; nb = n0 - 2048;
  } else {
    src = Wg1; N = 16; stride = 16; nb = n0 - 3072;
  }
  int tx = threadIdx.x & 31;
  int ty = threadIdx.x >> 5;
#pragma unroll
  for (int i = 0; i < 32; i += 8) {
    int k = k0 + ty + i;
    int n = nb + tx;
    tile[ty + i][tx] = (n < N) ? src[(size_t)k * stride + n] : 0.0f;
  }
  __syncthreads();
#pragma unroll
  for (int i = 0; i < 32; i += 8) {
    Wall[(size_t)(n0 + ty + i) * K + k0 + tx] = f2bf(tile[tx][ty + i]);
  }
}

// --- per-batch bf16 transpose v2: 64x64 tiles, ushort4 global, stride-65 LDS ---
__global__ __launch_bounds__(256) void transpose_x_kernel(const ushort* __restrict__ xb,
                                                          ushort* __restrict__ xT) {
  __shared__ ushort tile[64 * 65];
  int b = blockIdx.z;
  int t0 = blockIdx.x * 64;
  int d0 = blockIdx.y * 64;
  int tx = threadIdx.x & 15;   // d quad
  int ty = threadIdx.x >> 4;   // 0..15
#pragma unroll
  for (int i = 0; i < 4; ++i) {
    int t = i * 16 + ty;
    ushort4 v = *(const ushort4*)(xb + ((size_t)b * Tt + t0 + t) * Dd + d0 + tx * 4);
    tile[t * 65 + tx * 4 + 0] = v.x;
    tile[t * 65 + tx * 4 + 1] = v.y;
    tile[t * 65 + tx * 4 + 2] = v.z;
    tile[t * 65 + tx * 4 + 3] = v.w;
  }
  __syncthreads();
  int tw = threadIdx.x & 15;   // t quad
  int dw = threadIdx.x >> 4;   // 0..15
#pragma unroll
  for (int j = 0; j < 4; ++j) {
    int d = j * 16 + dw;
    ushort4 o;
    o.x = tile[(tw * 4 + 0) * 65 + d];
    o.y = tile[(tw * 4 + 1) * 65 + d];
    o.z = tile[(tw * 4 + 2) * 65 + d];
    o.w = tile[(tw * 4 + 3) * 65 + d];
    *(ushort4*)(xT + ((size_t)b * Dd + d0 + d) * Tt + t0 + tw * 4) = o;
  }
}

// ======== 128x64-tile MFMA GEMM building blocks (BK=32) ========
// A tile 128x32 (8KB LDS), B tile 64x32 (4KB LDS); 4 waves: wm=wave>>1 (2x64 rows),
// wn=wave&1 (2x32 cols); per wave acc[4][2]. ~4 blocks/CU occupancy (vs 1.1 at 128x128).

// ------- GEMM1: xb[8192][2048] @ Wallk[1152][2048]^T; bn<16 -> kT[bh][kd][t], else g1 -------
// grid dim3(64,18): bm fastest => A-tile sharers (idx stride 64 == 0 mod 8) on same XCD.
__global__ __launch_bounds__(256) void gemm_kg_kernel(const ushort* __restrict__ A,
                                                      const ushort* __restrict__ Wallk,
                                                      ushort* __restrict__ kT,
                                                      float* __restrict__ g1) {
  __shared__ __align__(16) ushort As[128 * 32];
  __shared__ __align__(16) ushort Bs[64 * 32];
  int bm = blockIdx.x;
  int bn = blockIdx.y;  // 0..17
  int wave = threadIdx.x >> 6;
  int lane = threadIdx.x & 63;
  int wm = wave >> 1, wn = wave & 1;
  int lrow = lane & 15;
  int quad = lane >> 4;
  int rowInChunk = lane >> 2;
  int kElem = (lane & 3) * 8;

  f32x4 acc[4][2] = {};
  for (int kk = 0; kk < Dd; kk += 32) {
#pragma unroll
    for (int r = 0; r < 2; ++r) {
      int chunk = wave * 2 + r;
      int arow = chunk * 16 + rowInChunk;
      const ushort* ga = A + ((size_t)(bm * 128 + arow)) * Dd + kk + kElem;
      __builtin_amdgcn_global_load_lds((__attribute__((address_space(1))) void*)ga,
                                       (__attribute__((address_space(3))) void*)(As + chunk * 512),
                                       16, 0, 0);
    }
    {
      int brow = wave * 16 + rowInChunk;
      const ushort* gb = Wallk + ((size_t)(bn * 64 + brow)) * Dd + kk + kElem;
      __builtin_amdgcn_global_load_lds((__attribute__((address_space(1))) void*)gb,
                                       (__attribute__((address_space(3))) void*)(Bs + wave * 512),
                                       16, 0, 0);
    }
    __syncthreads();
    bf16x8 af[4], bfr[2];
#pragma unroll
    for (int i = 0; i < 4; ++i) af[i] = *(const bf16x8*)(As + (wm * 64 + i * 16 + lrow) * 32 + quad * 8);
#pragma unroll
    for (int j = 0; j < 2; ++j) bfr[j] = *(const bf16x8*)(Bs + (wn * 32 + j * 16 + lrow) * 32 + quad * 8);
#pragma unroll
    for (int i = 0; i < 4; ++i)
#pragma unroll
      for (int j = 0; j < 2; ++j)
        acc[i][j] = __builtin_amdgcn_mfma_f32_16x16x32_bf16(af[i], bfr[j], acc[i][j], 0, 0, 0);
    __syncthreads();
  }

#pragma unroll
  for (int i = 0; i < 4; ++i) {
    int m0 = bm * 128 + wm * 64 + i * 16 + quad * 4;
    int b = m0 >> 11, tloc = m0 & 2047;
#pragma unroll
    for (int j = 0; j < 2; ++j) {
      int col = bn * 64 + wn * 32 + j * 16 + lrow;
      if (bn < 16) {  // k: kT[bh][kd][t]
        int h = col >> 7, kd = col & 127;
        ushort4 o;
        o.x = f2bf(acc[i][j][0]);
        o.y = f2bf(acc[i][j][1]);
        o.z = f2bf(acc[i][j][2]);
        o.w = f2bf(acc[i][j][3]);
        *(ushort4*)(kT + ((size_t)((b * 8 + h) * 128 + kd)) * 2048 + tloc) = o;
      } else {  // g1 fp32 [8192][128]; col in [1024,1152)
        int cg = col - 1024;
#pragma unroll
        for (int rg = 0; rg < 4; ++rg)
          g1[(size_t)(m0 + rg) * 128 + cg] = acc[i][j][rg];
      }
    }
  }
}

// ------- GEMM2: Y[bh][kd][d] = kwT[bh](128 x 2048_t) @ xT[b](d x 2048_t)^T -------
// grid dim3(32 bn, 32 bh): bn fastest => xT-tile sharers (same b,bn; bh stride => idx
// stride 32 == 0 mod 8) on same XCD; 1024 blocks = 4 clean rounds.
__global__ __launch_bounds__(256) void gemm_y_kernel(const ushort* __restrict__ kwT,
                                                     const ushort* __restrict__ xT,
                                                     ushort* __restrict__ Y) {
  __shared__ __align__(16) ushort As[128 * 32];
  __shared__ __align__(16) ushort Bs[64 * 32];
  int bn = blockIdx.x;  // d tile 0..31
  int bh = blockIdx.y;  // 0..31
  int b = bh >> 3;
  const ushort* A = kwT + (size_t)bh * DKc * Tt;
  const ushort* B = xT + (size_t)b * Dd * Tt;
  int wave = threadIdx.x >> 6;
  int lane = threadIdx.x & 63;
  int wm = wave >> 1, wn = wave & 1;
  int lrow = lane & 15;
  int quad = lane >> 4;
  int rowInChunk = lane >> 2;
  int kElem = (lane & 3) * 8;

  f32x4 acc[4][2] = {};
  for (int kk = 0; kk < Tt; kk += 32) {
#pragma unroll
    for (int r = 0; r < 2; ++r) {
      int chunk = wave * 2 + r;
      int arow = chunk * 16 + rowInChunk;
      const ushort* ga = A + (size_t)arow * Tt + kk + kElem;
      __builtin_amdgcn_global_load_lds((__attribute__((address_space(1))) void*)ga,
                                       (__attribute__((address_space(3))) void*)(As + chunk * 512),
                                       16, 0, 0);
    }
    {
      int brow = wave * 16 + rowInChunk;
      const ushort* gb = B + ((size_t)(bn * 64 + brow)) * Tt + kk + kElem;
      __builtin_amdgcn_global_load_lds((__attribute__((address_space(1))) void*)gb,
                                       (__attribute__((address_space(3))) void*)(Bs + wave * 512),
                                       16, 0, 0);
    }
    __syncthreads();
    bf16x8 af[4], bfr[2];
#pragma unroll
    for (int i = 0; i < 4; ++i) af[i] = *(const bf16x8*)(As + (wm * 64 + i * 16 + lrow) * 32 + quad * 8);
#pragma unroll
    for (int j = 0; j < 2; ++j) bfr[j] = *(const bf16x8*)(Bs + (wn * 32 + j * 16 + lrow) * 32 + quad * 8);
#pragma unroll
    for (int i = 0; i < 4; ++i)
#pragma unroll
      for (int j = 0; j < 2; ++j)
        acc[i][j] = __builtin_amdgcn_mfma_f32_16x16x32_bf16(af[i], bfr[j], acc[i][j], 0, 0, 0);
    __syncthreads();
  }

#pragma unroll
  for (int i = 0; i < 4; ++i) {
    int row0 = wm * 64 + i * 16 + quad * 4;  // kd
#pragma unroll
    for (int j = 0; j < 2; ++j) {
      int col = bn * 64 + wn * 32 + j * 16 + lrow;  // d
#pragma unroll
      for (int rg = 0; rg < 4; ++rg)
        Y[((size_t)bh * DKc + row0 + rg) * Dd + col] = f2bf(acc[i][j][rg]);
    }
  }
}

// ------- GEMM3 split-K: Spart[ks][bh] = Y[bh](128 x 512_d) @ WvT_h(64 x 512_d)^T -------
// grid dim3(4 bn, 32 bh, 4 ks) = 512 blocks = 2 clean rounds.
__global__ __launch_bounds__(256) void gemm_out_sk_kernel(const ushort* __restrict__ Y,
                                                          const ushort* __restrict__ WvT,
                                                          float* __restrict__ Spart) {
  __shared__ __align__(16) ushort As[128 * 32];
  __shared__ __align__(16) ushort Bs[64 * 32];
  int bn = blockIdx.x;  // vv tile 0..3
  int bh = blockIdx.y;  // 0..31
  int ks = blockIdx.z;  // 0..3
  int h = bh & 7;
  const ushort* A = Y + (size_t)bh * DKc * Dd;
  const ushort* B = WvT + (size_t)(h * DVc + bn * 64) * Dd;
  int wave = threadIdx.x >> 6;
  int lane = threadIdx.x & 63;
  int wm = wave >> 1, wn = wave & 1;
  int lrow = lane & 15;
  int quad = lane >> 4;
  int rowInChunk = lane >> 2;
  int kElem = (lane & 3) * 8;

  f32x4 acc[4][2] = {};
  int kk0 = ks * 512;
  for (int kk = kk0; kk < kk0 + 512; kk += 32) {
#pragma unroll
    for (int r = 0; r < 2; ++r) {
      int chunk = wave * 2 + r;
      int arow = chunk * 16 + rowInChunk;
      const ushort* ga = A + (size_t)arow * Dd + kk + kElem;
      __builtin_amdgcn_global_load_lds((__attribute__((address_space(1))) void*)ga,
                                       (__attribute__((address_space(3))) void*)(As + chunk * 512),
                                       16, 0, 0);
    }
    {
      int brow = wave * 16 + rowInChunk;
      const ushort* gb = B + (size_t)brow * Dd + kk + kElem;
      __builtin_amdgcn_global_load_lds((__attribute__((address_space(1))) void*)gb,
                                       (__attribute__((address_space(3))) void*)(Bs + wave * 512),
                                       16, 0, 0);
    }
    __syncthreads();
    bf16x8 af[4], bfr[2];
#pragma unroll
    for (int i = 0; i < 4; ++i) af[i] = *(const bf16x8*)(As + (wm * 64 + i * 16 + lrow) * 32 + quad * 8);
#pragma unroll
    for (int j = 0; j < 2; ++j) bfr[j] = *(const bf16x8*)(Bs + (wn * 32 + j * 16 + lrow) * 32 + quad * 8);
#pragma unroll
    for (int i = 0; i < 4; ++i)
#pragma unroll
      for (int j = 0; j < 2; ++j)
        acc[i][j] = __builtin_amdgcn_mfma_f32_16x16x32_bf16(af[i], bfr[j], acc[i][j], 0, 0, 0);
    __syncthreads();
  }

  float* Sp = Spart + ((size_t)ks * NBH + bh) * (DKc * DVc);
#pragma unroll
  for (int i = 0; i < 4; ++i) {
    int row0 = wm * 64 + i * 16 + quad * 4;  // kd
#pragma unroll
    for (int j = 0; j < 2; ++j) {
      int col = bn * 64 + wn * 32 + j * 16 + lrow;  // vv
#pragma unroll
      for (int rg = 0; rg < 4; ++rg)
        Sp[(size_t)(row0 + rg) * DVc + col] = acc[i][j][rg];
    }
  }
}

// ------------- out = S0*eBtot + sum_ks Spart -------------
__global__ __launch_bounds__(256) void reduce_kernel(const float* __restrict__ Spart,
                                                     const float* __restrict__ eBtot,
                                                     const float* __restrict__ S0,
                                                     float* __restrict__ out) {
  int i4 = blockIdx.x * 256 + threadIdx.x;
  int idx = i4 * 4;
  int bh = idx >> 15;
  int kd = (idx >> 8) & 127;
  float e = eBtot[bh * DKc + kd];
  float4 a = ((const float4*)S0)[i4];
  float4 p0 = ((const float4*)Spart)[i4];
  float4 p1 = ((const float4*)Spart)[i4 + 262144];
  float4 p2 = ((const float4*)Spart)[i4 + 524288];
  float4 p3 = ((const float4*)Spart)[i4 + 786432];
  float4 r;
  r.x = a.x * e + p0.x + p1.x + p2.x + p3.x;
  r.y = a.y * e + p0.y + p1.y + p2.y + p3.y;
  r.z = a.z * e + p0.z + p1.z + p2.z + p3.z;
  r.w = a.w * e + p0.w + p1.w + p2.w + p3.w;
  ((float4*)out)[i4] = r;
}

// ------------- chunk gate sums: L[bh][n][kd] = sum_c logsig(g1@Wg2col + b)/GLN -------------
__global__ __launch_bounds__(128) void chunksum_kernel(const float* __restrict__ g1,
                                                       const float* __restrict__ Wg2,
                                                       const float* __restrict__ bg2,
                                                       float* __restrict__ L) {
  int n = blockIdx.x, bh = blockIdx.y;
  int b = bh >> 3, h = bh & 7;
  int t = threadIdx.x;  // kd
  int kdg = h * DKc + t;
  int trow = b * Tt + n * CHUNKc;
  __shared__ float g1s[CHUNKc * 16];
#pragma unroll
  for (int i = 0; i < 8; ++i) {
    int flat = i * 128 + t;
    int c = flat >> 4, r = flat & 15;
    g1s[flat] = g1[(size_t)(trow + c) * 128 + r];
  }
  float wc[16];
#pragma unroll
  for (int r = 0; r < 16; ++r) wc[r] = Wg2[r * KDIM + kdg];
  float bias = bg2[kdg];
  __syncthreads();
  float sum = 0.f;
  for (int c = 0; c < CHUNKc; ++c) {
    float dot = bias;
#pragma unroll
    for (int r = 0; r < 16; ++r) dot = fmaf(g1s[c * 16 + r], wc[r], dot);
    sum += logsig(dot) * (1.0f / GLNf);
  }
  L[((size_t)bh * NCHUNK + n) * DKc + t] = sum;
}

// ------------- weights: kwT[bh][kd][t] = bf16(k * exp(Btot - B_t)) in place; eBtot -------------
__global__ __launch_bounds__(128) void weight_kernel(const float* __restrict__ g1,
                                                     const float* __restrict__ Wg2,
                                                     const float* __restrict__ bg2,
                                                     const float* __restrict__ L,
                                                     ushort* __restrict__ kwT,
                                                     float* __restrict__ eBtot) {
  int n = blockIdx.x, bh = blockIdx.y;
  int b = bh >> 3, h = bh & 7;
  int t = threadIdx.x;  // kd
  int kdg = h * DKc + t;
  int trow = b * Tt + n * CHUNKc;
  __shared__ float g1s[CHUNKc * 16];
#pragma unroll
  for (int i = 0; i < 8; ++i) {
    int flat = i * 128 + t;
    int c = flat >> 4, r = flat & 15;
    g1s[flat] = g1[(size_t)(trow + c) * 128 + r];
  }
  float wc[16];
#pragma unroll
  for (int r = 0; r < 16; ++r) wc[r] = Wg2[r * KDIM + kdg];
  float bias = bg2[kdg];

  float suffix = 0.f, Ln = 0.f, Btot = 0.f;
#pragma unroll
  for (int m = 0; m < NCHUNK; ++m) {
    float Lm = L[((size_t)bh * NCHUNK + m) * DKc + t];
    if (m > n) suffix += Lm;
    if (m == n) Ln = Lm;
    Btot += Lm;
  }
  if (n == 0) eBtot[bh * DKc + t] = __expf(Btot);
  __syncthreads();

  float run = 0.f;
  size_t obase = ((size_t)bh * DKc + t) * (size_t)Tt + (size_t)n * CHUNKc;
  for (int cg = 0; cg < 8; ++cg) {
    ushort8v kw8;
    ushort8v k8 = *(const ushort8v*)(kwT + obase + cg * 8);
#pragma unroll
    for (int j = 0; j < 8; ++j) {
      int c = cg * 8 + j;
      float dot = bias;
#pragma unroll
      for (int r = 0; r < 16; ++r) dot = fmaf(g1s[c * 16 + r], wc[r], dot);
      run += logsig(dot) * (1.0f / GLNf);
      float w = __expf(suffix + Ln - run);  // exponent <= 0 always
      kw8[j] = f2bf(bf2f(k8[j]) * w);
    }
    *(ushort8v*)(kwT + obase + cg * 8) = kw8;
  }
}

extern "C" void kernel_launch(void* const* d_in, const int* in_sizes, int n_in,
                              void* d_out, int out_size, void* d_ws, size_t ws_size,
                              hipStream_t stream) {
  const float* seg = (const float*)d_in[0];
  const float* norm_w = (const float*)d_in[1];
  const float* Wk = (const float*)d_in[2];
  const float* Wv = (const float*)d_in[3];
  const float* Wg1 = (const float*)d_in[4];
  const float* Wg2 = (const float*)d_in[5];
  const float* bg2 = (const float*)d_in[6];
  const float* S0 = (const float*)d_in[7];
  float* out = (float*)d_out;
  char* ws = (char*)d_ws;

  // ---- workspace 93.65 MiB (proven available R6-R9) ----
  // regA 32MiB: xb bf16[8192][2048] -> (dead after gemm_kg + transpose_x) Y bf16[32][128][2048]
  // regB 32MiB: xT bf16[4][2048][2048]
  // regD 16MiB: kT bf16[32][128][2048] -> kwT (in-place RMW) -> (dead after gemm_y)
  //             Spart f32[4][32][128][256]
  // regC 12.5MiB: W_allT bf16[3200][2048]; then Lbuf f32[32][32][128], eBtot f32[32][128]
  // d_out: g1 f32[8192][128] (dead before reduce writes d_out)
  char* regA = ws;
  char* regB = ws + (size_t)32 * 1024 * 1024;
  char* regD = ws + (size_t)64 * 1024 * 1024;
  char* regC = ws + (size_t)80 * 1024 * 1024;
  float* Lbuf = (float*)(regC + 13107200);
  float* eBtot = (float*)(regC + 13107200 + 524288);

  ushort* xb = (ushort*)regA;
  ushort* Y = (ushort*)regA;                   // after xb dead
  ushort* xT = (ushort*)regB;
  ushort* kwT = (ushort*)regD;
  float* Spart = (float*)regD;                 // after kwT dead (post gemm_y)
  ushort* Wall = (ushort*)regC;
  ushort* Wallk = Wall + (size_t)2048 * 2048;  // rows 2048.. = [Wk^T ; Wg1^T]
  float* g1buf = (float*)d_out;

  rmsnorm_kernel<<<Mrows, 256, 0, stream>>>(seg, norm_w, xb);
  transpose_all_kernel<<<dim3(64, 100), 256, 0, stream>>>(Wv, Wk, Wg1, Wall);
  transpose_x_kernel<<<dim3(32, 32, 4), 256, 0, stream>>>(xb, xT);
  gemm_kg_kernel<<<dim3(64, 18), 256, 0, stream>>>(xb, Wallk, kwT, g1buf);
  chunksum_kernel<<<dim3(NCHUNK, NBH), 128, 0, stream>>>(g1buf, Wg2, bg2, Lbuf);
  weight_kernel<<<dim3(NCHUNK, NBH), 128, 0, stream>>>(g1buf, Wg2, bg2, Lbuf, kwT, eBtot);
  gemm_y_kernel<<<dim3(32, 32), 256, 0, stream>>>(kwT, xT, Y);
  gemm_out_sk_kernel<<<dim3(4, 32, 4), 256, 0, stream>>>(Y, Wall, Spart);
  reduce_kernel<<<1024, 256, 0, stream>>>(Spart, eBtot, S0, out);
}